// Round 5
// baseline (667.345 us; speedup 1.0000x reference)
//
#include <hip/hip_runtime.h>
#include <stdint.h>

// Sizes (fixed by the problem)
#define N_PATCH 8192
#define DIM     1024
#define HID     512
#define NHEAD   16

using short8 = __attribute__((ext_vector_type(8))) short;
using f32x16 = __attribute__((ext_vector_type(16))) float;

#define VMC(n) asm volatile("s_waitcnt vmcnt(" #n ")" ::: "memory")
#define BAR()  __builtin_amdgcn_s_barrier()

__device__ __forceinline__ unsigned short f2bf(float f) {
  unsigned u = __float_as_uint(f);
  u = u + 0x7fffu + ((u >> 16) & 1u);   // round-to-nearest-even
  return (unsigned short)(u >> 16);
}

// global -> LDS direct copy, 16B per lane (CK addrspace-cast pattern)
__device__ __forceinline__ void gload_lds16(const void* g, void* l) {
  __builtin_amdgcn_global_load_lds(
      reinterpret_cast<const __attribute__((address_space(1))) void*>(
          reinterpret_cast<uintptr_t>(g)),
      reinterpret_cast<__attribute__((address_space(3))) void*>(
          reinterpret_cast<uintptr_t>(l)),
      16, 0, 0);
}

// ---------------- x fp32 -> bf16 ----------------
__global__ void convert_x_kernel(const float* __restrict__ x,
                                 unsigned short* __restrict__ xb) {
  const int total4 = (N_PATCH * DIM) / 4;
  for (int i = blockIdx.x * blockDim.x + threadIdx.x; i < total4;
       i += gridDim.x * blockDim.x) {
    float4 v = ((const float4*)x)[i];
    ushort4 o;
    o.x = f2bf(v.x); o.y = f2bf(v.y); o.z = f2bf(v.z); o.w = f2bf(v.w);
    ((ushort4*)xb)[i] = o;
  }
}

// ---------------- pack Vw/Uw -> Wpt[k][c][d] bf16 (transposed, V/U interleaved per 16 cols) ----
// c = (h>>4)*32 + u*16 + (h&15),  u=0:V  u=1:U
__global__ void pack_w_kernel(const float* __restrict__ Vw,
                              const float* __restrict__ Uw,
                              unsigned short* __restrict__ Wpt) {
  __shared__ unsigned short T[128][68];
  const int hc = blockIdx.x;   // 0..7   (h chunk of 64)
  const int dc = blockIdx.y;   // 0..15  (d chunk of 64)
  const int k  = blockIdx.z;   // head
  const int t  = threadIdx.x;  // 256
  const int d0 = dc * 64, h0 = hc * 64;
  const size_t base = (size_t)k * DIM * HID;
  for (int u = 0; u < 2; ++u) {
    const float* W = u ? Uw : Vw;
    #pragma unroll
    for (int i = 0; i < 16; ++i) {
      int idx = i * 256 + t;
      int dd = idx >> 6, hh = idx & 63;
      float v = W[base + (size_t)(d0 + dd) * HID + h0 + hh];
      int cl = ((hh >> 4) << 5) + (u << 4) + (hh & 15);
      T[cl][dd] = f2bf(v);
    }
  }
  __syncthreads();
  const size_t obase = ((size_t)k * 1024 + hc * 128) * DIM + d0;
  #pragma unroll
  for (int i = 0; i < 8; ++i) {
    int idx = i * 1024 + t * 4;
    int cl = idx >> 6, dd = idx & 63;
    ushort4 o;
    o.x = T[cl][dd]; o.y = T[cl][dd + 1]; o.z = T[cl][dd + 2]; o.w = T[cl][dd + 3];
    *(ushort4*)&Wpt[obase + (size_t)cl * DIM + dd] = o;
  }
}

// ---------------- main GEMM + gated epilogue -> score partials ----------------
// 256x256 tile, BK=64, 8 waves (2M x 4N), 4 phases/K-tile, 3-bit XOR swizzle,
// v_mfma_f32_32x32x16_bf16 (2495 TF pipe), B held in regs, counted vmcnt(8)/K-tile.
__global__ __launch_bounds__(512, 2) void gemm_scores_kernel(
    const unsigned short* __restrict__ xb,
    const unsigned short* __restrict__ Wpt,
    const float* __restrict__ Vb, const float* __restrict__ Ub,
    const float* __restrict__ ww, float* __restrict__ part) {
  __shared__ unsigned short As[2][16384];   // 64 KB
  __shared__ unsigned short Bs[2][16384];   // 64 KB
  const int bid = blockIdx.x;
  const int ct = (bid & 7) * 8 + (bid >> 8);   // XCD-chunked: 8 col-panels per XCD
  const int mt = (bid >> 3) & 31;
  const int kh = ct >> 2, cb = ct & 3;
  const int tid = threadIdx.x;
  const int wv = tid >> 6, lane = tid & 63;
  const int wr = wv >> 2, wc = wv & 3;         // 2 x 4 wave grid
  const int l15 = lane & 15;
  const int rl  = lane & 31;                   // row-in-fragment (32x32)
  const int khf = lane >> 5;                   // k-half

  const unsigned short* Ab = xb + (size_t)mt * 256 * DIM;
  const unsigned short* Bb = Wpt + (size_t)ct * 256 * DIM;

  f32x16 acc[4][2];   // [mf 0..3 = rows mf*32][nf 0..1 = cols nf*32]
  #pragma unroll
  for (int i = 0; i < 4; ++i)
    #pragma unroll
    for (int j = 0; j < 2; ++j)
      #pragma unroll
      for (int r = 0; r < 16; ++r) acc[i][j][r] = 0.f;

  // ---- staging: chunk = 16KB, 2 x gload_lds16 per thread, linear LDS dest,
  //      inverse-swizzled global source (elem k ^= ((r>>1)&7)<<3) ----
  auto stageA = [&](int t, int mh) {
    const int buf = t & 1, db = t << 6;
    #pragma unroll
    for (int j = 0; j < 2; ++j) {
      const int r = j * 128 + mh * 64 + wv * 8 + (lane >> 3);
      const int ksrc = ((lane & 7) * 8) ^ (((r >> 1) & 7) << 3);
      char* lds = (char*)&As[buf][0] + j * 16384 + mh * 8192 + wv * 1024;
      gload_lds16(Ab + (size_t)r * DIM + db + ksrc, lds);
    }
  };
  auto stageB = [&](int t, int nh) {
    const int buf = t & 1, db = t << 6;
    #pragma unroll
    for (int j = 0; j < 2; ++j) {
      const int piece = j * 2 + wr;
      const int r = piece * 64 + nh * 32 + (wv & 3) * 8 + (lane >> 3);
      const int ksrc = ((lane & 7) * 8) ^ (((r >> 1) & 7) << 3);
      char* lds = (char*)&Bs[buf][0] + piece * 8192 + nh * 4096 + (wv & 3) * 1024;
      gload_lds16(Bb + (size_t)r * DIM + db + ksrc, lds);
    }
  };

  // ---- hoisted swizzled read addresses (per-lane constants) ----
  // byte(row, kidx) = row*128 + (kidx<<4 ^ swz), swz = ((rl>>1)&7)<<4
  // kidx = kt*2 + khf; kt<<5 bits are disjoint from khf<<4 -> per-kt pure XOR
  const int swz = ((rl >> 1) & 7) << 4;
  const int aAddr = wr * 16384 + rl * 128 + ((khf << 4) ^ swz);
  const int bAddr = wc * 8192 + rl * 128 + ((khf << 4) ^ swz);

  short8 a[2][4], b0[4], b1[4];
  auto LDA32 = [&](int buf, int mh) {          // 8 x ds_read_b128
    const char* base = (const char*)&As[buf][0] + mh * 8192;
    #pragma unroll
    for (int mf2 = 0; mf2 < 2; ++mf2)
      #pragma unroll
      for (int kt = 0; kt < 4; ++kt)
        a[mf2][kt] = *(const short8*)(base + mf2 * 4096 + (aAddr ^ (kt << 5)));
  };
  auto LDB32 = [&](int buf, int nh, short8* b) {  // 4 x ds_read_b128
    const char* base = (const char*)&Bs[buf][0] + nh * 4096;
    #pragma unroll
    for (int kt = 0; kt < 4; ++kt)
      b[kt] = *(const short8*)(base + (bAddr ^ (kt << 5)));
  };
  auto MFMA8 = [&](int mh, int nh, const short8* b) {  // 8 MFMA: 64 rows x 32 cols x K=64
    __builtin_amdgcn_s_setprio(1);
    #pragma unroll
    for (int kt = 0; kt < 4; ++kt)
      #pragma unroll
      for (int mf2 = 0; mf2 < 2; ++mf2)
        acc[mh * 2 + mf2][nh] = __builtin_amdgcn_mfma_f32_32x32x16_bf16(
            a[mf2][kt], b[kt], acc[mh * 2 + mf2][nh], 0, 0, 0);
    __builtin_amdgcn_s_setprio(0);
  };

  // ---- prologue: stage tiles 0 and 1 fully (16 loads), drain tile 0 ----
  stageA(0, 0); stageA(0, 1); stageB(0, 0); stageB(0, 1);
  stageA(1, 0); stageA(1, 1); stageB(1, 0); stageB(1, 1);
  VMC(8);
  BAR();

  // ---- main loop u=0..13: read tile u (buf), stage tile u+2 (same buf) ----
  // Region ledger: A0 read ph0 / staged ph1; B0 read ph0 / staged ph2;
  //                A1 read ph2 / staged ph3; B1 read ph1 / staged ph3.
  // VMC(8) at ph3 end drains tile u+1 (8 loads), leaves tile u+2 (8) in flight.
  for (int u = 0; u < 14; ++u) {
    const int buf = u & 1;
    LDA32(buf, 0); LDB32(buf, 0, b0);
    BAR(); MFMA8(0, 0, b0); BAR();
    LDB32(buf, 1, b1); stageA(u + 2, 0);
    BAR(); MFMA8(0, 1, b1); BAR();
    LDA32(buf, 1); stageB(u + 2, 0);
    BAR(); MFMA8(1, 0, b0); BAR();
    stageA(u + 2, 1); stageB(u + 2, 1);
    BAR(); MFMA8(1, 1, b1); VMC(8); BAR();
  }
  // ---- u=14 (buf 0): no staging; drain tile 15 at end ----
  LDA32(0, 0); LDB32(0, 0, b0);
  BAR(); MFMA8(0, 0, b0); BAR();
  LDB32(0, 1, b1);
  BAR(); MFMA8(0, 1, b1); BAR();
  LDA32(0, 1);
  BAR(); MFMA8(1, 0, b0); BAR();
  MFMA8(1, 1, b1); VMC(0); BAR();
  // ---- u=15 (buf 1): no staging, no vmcnt ----
  LDA32(1, 0); LDB32(1, 0, b0);
  BAR(); MFMA8(0, 0, b0); BAR();
  LDB32(1, 1, b1);
  BAR(); MFMA8(0, 1, b1); BAR();
  LDA32(1, 1);
  BAR(); MFMA8(1, 0, b0); BAR();
  MFMA8(1, 1, b1);

  // ---- gated epilogue (32x32 C/D layout: col=lane&31, row=(r&3)+8*(r>>2)+4*khf) ----
  // cols 0-15 of each 32-group = V(h), 16-31 = U(h): pair via shfl_xor(16).
  float partial[4][16];
  #pragma unroll
  for (int mf = 0; mf < 4; ++mf)
    #pragma unroll
    for (int r = 0; r < 16; ++r) partial[mf][r] = 0.f;

  #pragma unroll
  for (int nf = 0; nf < 2; ++nf) {
    const int hl = (cb * 8 + wc * 2 + nf) * 16 + l15;   // head-local h
    const float vb  = Vb[kh * HID + hl];
    const float ub  = Ub[kh * HID + hl];
    const float wwv = ww[kh * HID + hl];
    #pragma unroll
    for (int mf = 0; mf < 4; ++mf)
      #pragma unroll
      for (int r = 0; r < 16; ++r) {
        const float sv = acc[mf][nf][r];
        const float su = __shfl_xor(sv, 16, 64);        // U-col partner
        const float e2 = __expf(2.f * (sv + vb));
        const float av = 1.f - 2.f / (e2 + 1.f);        // tanh
        const float au = 1.f / (1.f + __expf(-(su + ub)));  // sigmoid
        partial[mf][r] += av * au * wwv;
      }
  }
  #pragma unroll
  for (int s = 1; s < 16; s <<= 1)
    #pragma unroll
    for (int mf = 0; mf < 4; ++mf)
      #pragma unroll
      for (int r = 0; r < 16; ++r)
        partial[mf][r] += __shfl_xor(partial[mf][r], s, 64);

  if ((lane & 31) == 0) {   // lanes 0 (rows +0) and 32 (rows +4)
    const int j = cb * 4 + wc;   // 0..15 partial slot
    float* dst = part + ((size_t)j * NHEAD + kh) * N_PATCH;
    const int rbase = mt * 256 + wr * 128;
    #pragma unroll
    for (int mf = 0; mf < 4; ++mf)
      #pragma unroll
      for (int r = 0; r < 16; ++r)
        dst[rbase + mf * 32 + (r & 3) + 8 * (r >> 2) + 4 * khf] = partial[mf][r];
  }
}

// ---------------- per-head: sum 16 partials -> scores + softmax stats ----------------
__global__ void scores_stats_kernel(const float* __restrict__ part,
                                    float* __restrict__ scores,
                                    float* __restrict__ stats) {
  const int k = blockIdx.x;
  const int t = threadIdx.x;
  __shared__ float shm[4], shs[4];
  float v[32];
  float mx = -1e30f;
  #pragma unroll
  for (int i = 0; i < 32; ++i) {
    const int n = i * 256 + t;
    float s = 0.f;
    #pragma unroll
    for (int j = 0; j < 16; ++j) s += part[((size_t)j * NHEAD + k) * N_PATCH + n];
    v[i] = s;
    scores[(size_t)k * N_PATCH + n] = s;
    mx = fmaxf(mx, s);
  }
  #pragma unroll
  for (int sft = 32; sft; sft >>= 1) mx = fmaxf(mx, __shfl_xor(mx, sft, 64));
  const int wv = t >> 6;
  if ((t & 63) == 0) shm[wv] = mx;
  __syncthreads();
  mx = fmaxf(fmaxf(shm[0], shm[1]), fmaxf(shm[2], shm[3]));
  float sum = 0.f;
  #pragma unroll
  for (int i = 0; i < 32; ++i) sum += __expf(v[i] - mx);
  #pragma unroll
  for (int sft = 32; sft; sft >>= 1) sum += __shfl_xor(sum, sft, 64);
  if ((t & 63) == 0) shs[wv] = sum;
  __syncthreads();
  if (t == 0) {
    stats[2 * k] = mx;
    stats[2 * k + 1] = shs[0] + shs[1] + shs[2] + shs[3];
  }
}

// ---------------- fused: w[n]=sum_k softmax_k(n); wp1/wp2 partial sums over rows ----
__global__ void weighted_part_kernel(const float* __restrict__ x,
                                     const float* __restrict__ scores,
                                     const float* __restrict__ stats,
                                     float* __restrict__ wp1,
                                     float* __restrict__ wp2) {
  __shared__ float wrow[256];
  const int d = blockIdx.x * 256 + threadIdx.x;  // grid.x = 4
  const int nc = blockIdx.y;                     // 32 chunks of 256 rows
  {
    const int n = nc * 256 + threadIdx.x;
    float s = 0.f;
    #pragma unroll
    for (int k = 0; k < NHEAD; ++k)
      s += __expf(scores[(size_t)k * N_PATCH + n] - stats[2 * k]) / stats[2 * k + 1];
    wrow[threadIdx.x] = s;
  }
  __syncthreads();
  float a1 = 0.f, a2 = 0.f;
  for (int i = 0; i < 256; ++i) {
    float xv = x[(size_t)(nc * 256 + i) * DIM + d];
    a1 += wrow[i] * xv;
    a2 += xv;
  }
  wp1[nc * DIM + d] = a1;
  wp2[nc * DIM + d] = a2;
}

__global__ void reduce_vec_kernel(const float* __restrict__ wp1,
                                  const float* __restrict__ wp2,
                                  float* __restrict__ y1,
                                  float* __restrict__ mvec) {
  int d = blockIdx.x * 256 + threadIdx.x;
  float s1 = 0.f, s2 = 0.f;
  #pragma unroll
  for (int i = 0; i < 32; ++i) {
    s1 += wp1[i * DIM + d];
    s2 += wp2[i * DIM + d];
  }
  y1[d] = s1;
  mvec[d] = s2 * (1.f / (float)N_PATCH);
}

// ---------------- split-K GEMV partial ----------------
__global__ void gemv_part_kernel(const float* __restrict__ in,
                                 const float* __restrict__ W,
                                 float* __restrict__ part, int In, int Out) {
  int j = blockIdx.x * blockDim.x + threadIdx.x;
  int kc = blockIdx.y;
  int chunk = In / gridDim.y;
  if (j >= Out) return;
  const float* Wp = W + (size_t)(kc * chunk) * Out + j;
  float acc = 0.f;
  for (int d = 0; d < chunk; ++d) acc += in[kc * chunk + d] * Wp[(size_t)d * Out];
  part[kc * Out + j] = acc;
}

__global__ void gemv_combine_kernel(const float* __restrict__ part, int nkc,
                                    const float* __restrict__ bias,
                                    const float* __restrict__ extra, float scale,
                                    int do_relu, float* __restrict__ out, int Out) {
  int j = blockIdx.x * blockDim.x + threadIdx.x;
  if (j >= Out) return;
  float v = bias[j];
  for (int kc = 0; kc < nkc; ++kc) v += part[kc * Out + j];
  if (extra) v += extra[j];
  v *= scale;
  if (do_relu) v = fmaxf(v, 0.f);
  out[j] = v;
}

// ---------------- final: logits = c3 @ cW4 + cb4 ; softmax -> out ----------------
__global__ void final_head_kernel(const float* __restrict__ c3,
                                  const float* __restrict__ W,
                                  const float* __restrict__ b,
                                  float* __restrict__ out) {
  __shared__ float logits[9];
  int t = threadIdx.x;
  if (t < 9) {
    float acc = b[t];
    for (int d = 0; d < 256; ++d) acc += c3[d] * W[d * 9 + t];
    logits[t] = acc;
  }
  __syncthreads();
  if (t == 0) {
    float mx = logits[0];
    for (int j = 1; j < 9; ++j) mx = fmaxf(mx, logits[j]);
    float e[9], s = 0.f;
    for (int j = 0; j < 9; ++j) { e[j] = expf(logits[j] - mx); s += e[j]; }
    for (int j = 0; j < 9; ++j) out[j] = e[j] / s;
  }
}

extern "C" void kernel_launch(void* const* d_in, const int* in_sizes, int n_in,
                              void* d_out, int out_size, void* d_ws, size_t ws_size,
                              hipStream_t stream) {
  (void)in_sizes; (void)n_in; (void)out_size; (void)ws_size;
  const float* x   = (const float*)d_in[0];
  const float* Vw  = (const float*)d_in[1];
  const float* Vb  = (const float*)d_in[2];
  const float* Uw  = (const float*)d_in[3];
  const float* Ub  = (const float*)d_in[4];
  const float* ww  = (const float*)d_in[5];
  // d_in[6] = wb: constant per head -> softmax invariant -> unused
  const float* pW1 = (const float*)d_in[7];
  const float* pb1 = (const float*)d_in[8];
  const float* pW2 = (const float*)d_in[9];
  const float* pb2 = (const float*)d_in[10];
  const float* cW1 = (const float*)d_in[11];
  const float* cb1 = (const float*)d_in[12];
  const float* cW2 = (const float*)d_in[13];
  const float* cb2 = (const float*)d_in[14];
  const float* cW3 = (const float*)d_in[15];
  const float* cb3 = (const float*)d_in[16];
  const float* cW4 = (const float*)d_in[17];
  const float* cb4 = (const float*)d_in[18];
  float* out = (float*)d_out;

  char* ws = (char*)d_ws;
  size_t o = 0;
  auto alloc = [&](size_t bytes) -> char* {
    char* p = ws + o;
    o += (bytes + 255) & ~(size_t)255;
    return p;
  };
  unsigned short* xb  = (unsigned short*)alloc((size_t)N_PATCH * DIM * 2);      // 16 MB
  unsigned short* Wpt = (unsigned short*)alloc((size_t)NHEAD * 1024 * DIM * 2); // 32 MB
  float* part   = (float*)alloc((size_t)16 * NHEAD * N_PATCH * 4);              // 8 MB
  float* scores = (float*)alloc((size_t)NHEAD * N_PATCH * 4);
  float* stats  = (float*)alloc(NHEAD * 2 * 4);
  float* wp1    = (float*)alloc(32 * DIM * 4);
  float* wp2    = (float*)alloc(32 * DIM * 4);
  float* y1     = (float*)alloc(DIM * 4);
  float* mvec   = (float*)alloc(DIM * 4);
  float* h1part = (float*)alloc(16 * HID * 4);
  float* h1     = (float*)alloc(HID * 4);
  float* agpart = (float*)alloc(8 * DIM * 4);
  float* aggr   = (float*)alloc(DIM * 4);
  float* c1part = (float*)alloc(16 * 1024 * 4);
  float* c1     = (float*)alloc(1024 * 4);
  float* c2part = (float*)alloc(16 * 512 * 4);
  float* c2     = (float*)alloc(512 * 4);
  float* c3part = (float*)alloc(8 * 256 * 4);
  float* c3     = (float*)alloc(256 * 4);

  convert_x_kernel<<<2048, 256, 0, stream>>>(x, xb);
  pack_w_kernel<<<dim3(8, 16, 16), 256, 0, stream>>>(Vw, Uw, Wpt);
  gemm_scores_kernel<<<2048, 512, 0, stream>>>(xb, Wpt, Vb, Ub, ww, part);
  scores_stats_kernel<<<16, 256, 0, stream>>>(part, scores, stats);
  weighted_part_kernel<<<dim3(4, 32), 256, 0, stream>>>(x, scores, stats, wp1, wp2);
  reduce_vec_kernel<<<4, 256, 0, stream>>>(wp1, wp2, y1, mvec);
  gemv_part_kernel<<<dim3(2, 16), 256, 0, stream>>>(mvec, pW1, h1part, DIM, HID);
  gemv_combine_kernel<<<2, 256, 0, stream>>>(h1part, 16, pb1, nullptr, 1.f, 1, h1, HID);
  gemv_part_kernel<<<dim3(4, 8), 256, 0, stream>>>(h1, pW2, agpart, HID, DIM);
  gemv_combine_kernel<<<4, 256, 0, stream>>>(agpart, 8, pb2, y1, 1.f / 17.f, 0, aggr, DIM);
  gemv_part_kernel<<<dim3(4, 16), 256, 0, stream>>>(aggr, cW1, c1part, 1024, 1024);
  gemv_combine_kernel<<<4, 256, 0, stream>>>(c1part, 16, cb1, nullptr, 1.f, 1, c1, 1024);
  gemv_part_kernel<<<dim3(2, 16), 256, 0, stream>>>(c1, cW2, c2part, 1024, 512);
  gemv_combine_kernel<<<2, 256, 0, stream>>>(c2part, 16, cb2, nullptr, 1.f, 1, c2, 512);
  gemv_part_kernel<<<dim3(1, 8), 256, 0, stream>>>(c2, cW3, c3part, 512, 256);
  gemv_combine_kernel<<<1, 256, 0, stream>>>(c3part, 8, cb3, nullptr, 1.f, 1, c3, 256);
  final_head_kernel<<<1, 64, 0, stream>>>(c3, cW4, cb4, out);
}

// Round 6
// 562.355 us; speedup vs baseline: 1.1867x; 1.1867x over previous
//
#include <hip/hip_runtime.h>
#include <stdint.h>

// Sizes (fixed by the problem)
#define N_PATCH 8192
#define DIM     1024
#define HID     512
#define NHEAD   16

using short8 = __attribute__((ext_vector_type(8))) short;
using f32x4  = __attribute__((ext_vector_type(4))) float;

#define VMC(n) asm volatile("s_waitcnt vmcnt(" #n ")" ::: "memory")
#define BAR()  __builtin_amdgcn_s_barrier()

__device__ __forceinline__ unsigned short f2bf(float f) {
  unsigned u = __float_as_uint(f);
  u = u + 0x7fffu + ((u >> 16) & 1u);   // round-to-nearest-even
  return (unsigned short)(u >> 16);
}

// global -> LDS direct copy, 16B per lane (CK addrspace-cast pattern)
__device__ __forceinline__ void gload_lds16(const void* g, void* l) {
  __builtin_amdgcn_global_load_lds(
      reinterpret_cast<const __attribute__((address_space(1))) void*>(
          reinterpret_cast<uintptr_t>(g)),
      reinterpret_cast<__attribute__((address_space(3))) void*>(
          reinterpret_cast<uintptr_t>(l)),
      16, 0, 0);
}

// ---------------- fused prep: x fp32->bf16 (blocks 0..2047) + weight pack (2048..4095) ----
// pack: Wpt[k][c][d] bf16, c = (h>>4)*32 + u*16 + (h&15), u=0:V 1:U
__global__ void prep_kernel(const float* __restrict__ x,
                            unsigned short* __restrict__ xb,
                            const float* __restrict__ Vw,
                            const float* __restrict__ Uw,
                            unsigned short* __restrict__ Wpt) {
  __shared__ unsigned short T[128][68];
  const int bid = blockIdx.x;
  const int t = threadIdx.x;
  if (bid < 2048) {
    const int total4 = (N_PATCH * DIM) / 4;
    for (int i = bid * 256 + t; i < total4; i += 2048 * 256) {
      float4 v = ((const float4*)x)[i];
      ushort4 o;
      o.x = f2bf(v.x); o.y = f2bf(v.y); o.z = f2bf(v.z); o.w = f2bf(v.w);
      ((ushort4*)xb)[i] = o;
    }
    return;
  }
  const int idx = bid - 2048;
  const int hc = idx & 7;          // h chunk of 64
  const int dc = (idx >> 3) & 15;  // d chunk of 64
  const int k  = idx >> 7;         // head
  const int d0 = dc * 64, h0 = hc * 64;
  const size_t base = (size_t)k * DIM * HID;
  for (int u = 0; u < 2; ++u) {
    const float* W = u ? Uw : Vw;
    #pragma unroll
    for (int i = 0; i < 16; ++i) {
      int ii = i * 256 + t;
      int dd = ii >> 6, hh = ii & 63;
      float v = W[base + (size_t)(d0 + dd) * HID + h0 + hh];
      int cl = ((hh >> 4) << 5) + (u << 4) + (hh & 15);
      T[cl][dd] = f2bf(v);
    }
  }
  __syncthreads();
  const size_t obase = ((size_t)k * 1024 + hc * 128) * DIM + d0;
  #pragma unroll
  for (int i = 0; i < 8; ++i) {
    int ii = i * 1024 + t * 4;
    int cl = ii >> 6, dd = ii & 63;
    ushort4 o;
    o.x = T[cl][dd]; o.y = T[cl][dd + 1]; o.z = T[cl][dd + 2]; o.w = T[cl][dd + 3];
    *(ushort4*)&Wpt[obase + (size_t)cl * DIM + dd] = o;
  }
}

// ---------------- main GEMM + gated epilogue -> score partials ----------------
// 256x256 tile, BK=64, 8 waves (2M x 4N), 16x16x32 MFMA, 3-bit XOR swizzle
// (conflict-free), 2 phases/K-tile (4 barriers), counted vmcnt(8).
__global__ __launch_bounds__(512, 2) void gemm_scores_kernel(
    const unsigned short* __restrict__ xb,
    const unsigned short* __restrict__ Wpt,
    const float* __restrict__ Vb, const float* __restrict__ Ub,
    const float* __restrict__ ww, float* __restrict__ part) {
  __shared__ unsigned short As[2][16384];   // 64 KB
  __shared__ unsigned short Bs[2][16384];   // 64 KB
  const int bid = blockIdx.x;
  const int ct = (bid & 7) * 8 + (bid >> 8);   // XCD-chunked: 8 col-panels per XCD
  const int mt = (bid >> 3) & 31;
  const int kh = ct >> 2, cb = ct & 3;
  const int tid = threadIdx.x;
  const int wv = tid >> 6, lane = tid & 63;
  const int wr = wv >> 2, wc = wv & 3;         // 2 x 4 wave grid
  const int l15 = lane & 15, l4 = lane >> 4;

  const unsigned short* Ab = xb + (size_t)mt * 256 * DIM;
  const unsigned short* Bb = Wpt + (size_t)ct * 256 * DIM;

  const f32x4 vzero = {0.f, 0.f, 0.f, 0.f};
  f32x4 acc[8][4];
  #pragma unroll
  for (int i = 0; i < 8; ++i)
    #pragma unroll
    for (int j = 0; j < 4; ++j) acc[i][j] = vzero;

  // ---- staging: chunk = 16KB, 2 x gload_lds16 per thread, linear LDS dest,
  //      inverse-swizzled global source (elem k ^= ((r>>1)&7)<<3) ----
  auto stageA = [&](int t, int mh) {
    const int buf = t & 1, db = t << 6;
    #pragma unroll
    for (int j = 0; j < 2; ++j) {
      const int r = j * 128 + mh * 64 + wv * 8 + (lane >> 3);
      const int ksrc = ((lane & 7) * 8) ^ (((r >> 1) & 7) << 3);
      char* lds = (char*)&As[buf][0] + j * 16384 + mh * 8192 + wv * 1024;
      gload_lds16(Ab + (size_t)r * DIM + db + ksrc, lds);
    }
  };
  auto stageB = [&](int t, int nh) {
    const int buf = t & 1, db = t << 6;
    #pragma unroll
    for (int j = 0; j < 2; ++j) {
      const int piece = j * 2 + wr;
      const int r = piece * 64 + nh * 32 + (wv & 3) * 8 + (lane >> 3);
      const int ksrc = ((lane & 7) * 8) ^ (((r >> 1) & 7) << 3);
      char* lds = (char*)&Bs[buf][0] + piece * 8192 + nh * 4096 + (wv & 3) * 1024;
      gload_lds16(Bb + (size_t)r * DIM + db + ksrc, lds);
    }
  };

  // ---- hoisted swizzled read addresses (per-lane constants) ----
  const int swz = ((l15 >> 1) & 7) << 4;       // byte bits 4-6
  const int kb0 = (l4 * 16) ^ swz;
  const int aB0 = wr * 16384 + l15 * 128 + kb0;
  const int aB1 = aB0 ^ 64;                    // ks=1 flips byte-bit 6
  const int bB0 = wc * 8192 + l15 * 128 + kb0;
  const int bB1 = bB0 ^ 64;

  short8 a[8], b0[4], b1[4];
  auto LDA = [&](int buf, int mh) {            // 8 x ds_read_b128
    const char* base = (const char*)&As[buf][0] + mh * 8192;
    #pragma unroll
    for (int f = 0; f < 4; ++f) {
      a[f * 2 + 0] = *(const short8*)(base + aB0 + f * 2048);
      a[f * 2 + 1] = *(const short8*)(base + aB1 + f * 2048);
    }
  };
  auto LDB0 = [&](int buf) {                   // nh=0 -> b0
    const char* base = (const char*)&Bs[buf][0];
    #pragma unroll
    for (int g = 0; g < 2; ++g) {
      b0[g * 2 + 0] = *(const short8*)(base + bB0 + g * 2048);
      b0[g * 2 + 1] = *(const short8*)(base + bB1 + g * 2048);
    }
  };
  auto LDB1 = [&](int buf) {                   // nh=1 -> b1
    const char* base = (const char*)&Bs[buf][0] + 4096;
    #pragma unroll
    for (int g = 0; g < 2; ++g) {
      b1[g * 2 + 0] = *(const short8*)(base + bB0 + g * 2048);
      b1[g * 2 + 1] = *(const short8*)(base + bB1 + g * 2048);
    }
  };
  auto MFMAQ0 = [&](int mh) {                  // 16 MFMA, nh=0 quadrant
    __builtin_amdgcn_s_setprio(1);
    #pragma unroll
    for (int ks = 0; ks < 2; ++ks)
      #pragma unroll
      for (int f = 0; f < 4; ++f)
        #pragma unroll
        for (int g = 0; g < 2; ++g)
          acc[mh * 4 + f][g] = __builtin_amdgcn_mfma_f32_16x16x32_bf16(
              a[f * 2 + ks], b0[g * 2 + ks], acc[mh * 4 + f][g], 0, 0, 0);
    __builtin_amdgcn_s_setprio(0);
  };
  auto MFMAQ1 = [&](int mh) {                  // 16 MFMA, nh=1 quadrant
    __builtin_amdgcn_s_setprio(1);
    #pragma unroll
    for (int ks = 0; ks < 2; ++ks)
      #pragma unroll
      for (int f = 0; f < 4; ++f)
        #pragma unroll
        for (int g = 0; g < 2; ++g)
          acc[mh * 4 + f][2 + g] = __builtin_amdgcn_mfma_f32_16x16x32_bf16(
              a[f * 2 + ks], b1[g * 2 + ks], acc[mh * 4 + f][2 + g], 0, 0, 0);
    __builtin_amdgcn_s_setprio(0);
  };

  // ---- prologue: A0B0B1(0) [6], A1(0) [2], A0B0B1(1) [6]; drain first 6 ----
  stageA(0, 0); stageB(0, 0); stageB(0, 1);
  stageA(0, 1);
  stageA(1, 0); stageB(1, 0); stageB(1, 1);
  VMC(8);
  BAR();

  // ---- main loop u=0..13: 2 phases per K-tile ----
  // ph0: reads A0,B0,B1(u,buf); stages A1(u+1)->buf^1. Ends VMC(8): drains A1(u).
  // ph1: reads A1(u,buf);       stages A0,B0,B1(u+2)->buf. Ends VMC(8): drains A0B0B1(u+1).
  // Region-release: every stage is barrier-separated from the last read of its region.
  for (int u = 0; u < 14; ++u) {
    const int buf = u & 1;
    LDA(buf, 0); LDB0(buf); LDB1(buf); stageA(u + 1, 1);
    BAR(); MFMAQ0(0); MFMAQ1(0); VMC(8); BAR();
    LDA(buf, 1); stageA(u + 2, 0); stageB(u + 2, 0); stageB(u + 2, 1);
    BAR(); MFMAQ0(1); MFMAQ1(1); VMC(8); BAR();
  }
  // ---- u=14 (buf 0): last stage is A1(15) ----
  LDA(0, 0); LDB0(0); LDB1(0); stageA(15, 1);
  BAR(); MFMAQ0(0); MFMAQ1(0); VMC(8); BAR();
  LDA(0, 1);
  BAR(); MFMAQ0(1); MFMAQ1(1); VMC(2); BAR();
  // ---- u=15 (buf 1): no staging ----
  LDA(1, 0); LDB0(1); LDB1(1);
  BAR(); MFMAQ0(0); MFMAQ1(0); VMC(0); BAR();
  LDA(1, 1);
  BAR(); MFMAQ0(1); MFMAQ1(1);

  // ---- gated epilogue: tanh(AV+Vb)*sigmoid(AU+Ub)*ww, reduce 16 lanes ----
  float partial[8][4];
  #pragma unroll
  for (int f = 0; f < 8; ++f)
    #pragma unroll
    for (int r = 0; r < 4; ++r) partial[f][r] = 0.f;

  #pragma unroll
  for (int p = 0; p < 2; ++p) {
    const int hl = (cb * 8 + wc * 2 + p) * 16 + l15;   // head-local h
    const float vb  = Vb[kh * HID + hl];
    const float ub  = Ub[kh * HID + hl];
    const float wwv = ww[kh * HID + hl];
    #pragma unroll
    for (int f = 0; f < 8; ++f)
      #pragma unroll
      for (int r = 0; r < 4; ++r) {
        const float xv = acc[f][2 * p][r] + vb;
        const float e2 = __expf(2.f * xv);
        const float av = 1.f - 2.f / (e2 + 1.f);       // tanh
        const float xu = acc[f][2 * p + 1][r] + ub;
        const float au = 1.f / (1.f + __expf(-xu));    // sigmoid
        partial[f][r] += av * au * wwv;
      }
  }
  #pragma unroll
  for (int s = 1; s < 16; s <<= 1)
    #pragma unroll
    for (int f = 0; f < 8; ++f)
      #pragma unroll
      for (int r = 0; r < 4; ++r)
        partial[f][r] += __shfl_xor(partial[f][r], s, 64);

  if (l15 == 0) {
    const int j = cb * 4 + wc;   // 0..15 partial slot
    float* dst = part + ((size_t)j * NHEAD + kh) * N_PATCH;
    const int rbase = mt * 256 + wr * 128 + l4 * 4;
    #pragma unroll
    for (int f = 0; f < 8; ++f)
      #pragma unroll
      for (int r = 0; r < 4; ++r)
        dst[rbase + f * 16 + r] = partial[f][r];
  }
}

// ---------------- per-head: sum 16 partials -> scores + softmax stats ----------------
__global__ void scores_stats_kernel(const float* __restrict__ part,
                                    float* __restrict__ scores,
                                    float* __restrict__ stats) {
  const int k = blockIdx.x;
  const int t = threadIdx.x;
  __shared__ float shm[4], shs[4];
  float v[32];
  float mx = -1e30f;
  #pragma unroll
  for (int i = 0; i < 32; ++i) {
    const int n = i * 256 + t;
    float s = 0.f;
    #pragma unroll
    for (int j = 0; j < 16; ++j) s += part[((size_t)j * NHEAD + k) * N_PATCH + n];
    v[i] = s;
    scores[(size_t)k * N_PATCH + n] = s;
    mx = fmaxf(mx, s);
  }
  #pragma unroll
  for (int sft = 32; sft; sft >>= 1) mx = fmaxf(mx, __shfl_xor(mx, sft, 64));
  const int wv = t >> 6;
  if ((t & 63) == 0) shm[wv] = mx;
  __syncthreads();
  mx = fmaxf(fmaxf(shm[0], shm[1]), fmaxf(shm[2], shm[3]));
  float sum = 0.f;
  #pragma unroll
  for (int i = 0; i < 32; ++i) sum += __expf(v[i] - mx);
  #pragma unroll
  for (int sft = 32; sft; sft >>= 1) sum += __shfl_xor(sum, sft, 64);
  if ((t & 63) == 0) shs[wv] = sum;
  __syncthreads();
  if (t == 0) {
    stats[2 * k] = mx;
    stats[2 * k + 1] = shs[0] + shs[1] + shs[2] + shs[3];
  }
}

// ---------------- fused: w[n]=sum_k softmax_k(n); wp1/wp2 partial sums over rows ----
__global__ void weighted_part_kernel(const float* __restrict__ x,
                                     const float* __restrict__ scores,
                                     const float* __restrict__ stats,
                                     float* __restrict__ wp1,
                                     float* __restrict__ wp2) {
  __shared__ float wrow[128];
  const int d = blockIdx.x * 256 + threadIdx.x;  // grid.x = 4
  const int nc = blockIdx.y;                     // 64 chunks of 128 rows
  if (threadIdx.x < 128) {
    const int n = nc * 128 + threadIdx.x;
    float s = 0.f;
    #pragma unroll
    for (int k = 0; k < NHEAD; ++k)
      s += __expf(scores[(size_t)k * N_PATCH + n] - stats[2 * k]) / stats[2 * k + 1];
    wrow[threadIdx.x] = s;
  }
  __syncthreads();
  float a1 = 0.f, a2 = 0.f;
  for (int i = 0; i < 128; ++i) {
    float xv = x[(size_t)(nc * 128 + i) * DIM + d];
    a1 += wrow[i] * xv;
    a2 += xv;
  }
  wp1[nc * DIM + d] = a1;
  wp2[nc * DIM + d] = a2;
}

__global__ void reduce_vec_kernel(const float* __restrict__ wp1,
                                  const float* __restrict__ wp2,
                                  float* __restrict__ y1,
                                  float* __restrict__ mvec) {
  int d = blockIdx.x * 256 + threadIdx.x;
  float s1 = 0.f, s2 = 0.f;
  #pragma unroll
  for (int i = 0; i < 64; ++i) {
    s1 += wp1[i * DIM + d];
    s2 += wp2[i * DIM + d];
  }
  y1[d] = s1;
  mvec[d] = s2 * (1.f / (float)N_PATCH);
}

// ---------------- one-dispatch GEMV: in-block split-K (4 kc x 64 j), LDS reduce ----
__global__ void gemv_fused_kernel(const float* __restrict__ in,
                                  const float* __restrict__ W,
                                  const float* __restrict__ bias,
                                  const float* __restrict__ extra, float scale,
                                  int do_relu, float* __restrict__ out,
                                  int In, int Out) {
  __shared__ float red[4][64];
  const int jl = threadIdx.x & 63, kc = threadIdx.x >> 6;
  const int j = blockIdx.x * 64 + jl;
  const int chunk = In >> 2;
  const float* Wp = W + (size_t)(kc * chunk) * Out + j;
  const float* ip = in + kc * chunk;
  float acc = 0.f;
  #pragma unroll 4
  for (int d = 0; d < chunk; ++d) acc += ip[d] * Wp[(size_t)d * Out];
  if (kc) red[kc][jl] = acc;
  __syncthreads();
  if (kc == 0) {
    float v = bias[j] + acc + red[1][jl] + red[2][jl] + red[3][jl];
    if (extra) v += extra[j];
    v *= scale;
    if (do_relu) v = fmaxf(v, 0.f);
    out[j] = v;
  }
}

// ---------------- fused: c3 = relu(c2@cW3+cb3); logits = c3@cW4+cb4; softmax ----
__global__ void c3_final_kernel(const float* __restrict__ c2,
                                const float* __restrict__ W3,
                                const float* __restrict__ b3,
                                const float* __restrict__ W4,
                                const float* __restrict__ b4,
                                float* __restrict__ out) {
  __shared__ float c3s[256];
  __shared__ float logits[9];
  const int t = threadIdx.x;   // 256
  float acc = b3[t];
  #pragma unroll 4
  for (int d = 0; d < 512; ++d) acc += c2[d] * W3[(size_t)d * 256 + t];
  c3s[t] = fmaxf(acc, 0.f);
  __syncthreads();
  if (t < 9) {
    float l = b4[t];
    for (int d = 0; d < 256; ++d) l += c3s[d] * W4[d * 9 + t];
    logits[t] = l;
  }
  __syncthreads();
  if (t == 0) {
    float mx = logits[0];
    for (int j = 1; j < 9; ++j) mx = fmaxf(mx, logits[j]);
    float e[9], s = 0.f;
    for (int j = 0; j < 9; ++j) { e[j] = expf(logits[j] - mx); s += e[j]; }
    for (int j = 0; j < 9; ++j) out[j] = e[j] / s;
  }
}

extern "C" void kernel_launch(void* const* d_in, const int* in_sizes, int n_in,
                              void* d_out, int out_size, void* d_ws, size_t ws_size,
                              hipStream_t stream) {
  (void)in_sizes; (void)n_in; (void)out_size; (void)ws_size;
  const float* x   = (const float*)d_in[0];
  const float* Vw  = (const float*)d_in[1];
  const float* Vb  = (const float*)d_in[2];
  const float* Uw  = (const float*)d_in[3];
  const float* Ub  = (const float*)d_in[4];
  const float* ww  = (const float*)d_in[5];
  // d_in[6] = wb: constant per head -> softmax invariant -> unused
  const float* pW1 = (const float*)d_in[7];
  const float* pb1 = (const float*)d_in[8];
  const float* pW2 = (const float*)d_in[9];
  const float* pb2 = (const float*)d_in[10];
  const float* cW1 = (const float*)d_in[11];
  const float* cb1 = (const float*)d_in[12];
  const float* cW2 = (const float*)d_in[13];
  const float* cb2 = (const float*)d_in[14];
  const float* cW3 = (const float*)d_in[15];
  const float* cb3 = (const float*)d_in[16];
  const float* cW4 = (const float*)d_in[17];
  const float* cb4 = (const float*)d_in[18];
  float* out = (float*)d_out;

  char* ws = (char*)d_ws;
  size_t o = 0;
  auto alloc = [&](size_t bytes) -> char* {
    char* p = ws + o;
    o += (bytes + 255) & ~(size_t)255;
    return p;
  };
  unsigned short* xb  = (unsigned short*)alloc((size_t)N_PATCH * DIM * 2);      // 16 MB
  unsigned short* Wpt = (unsigned short*)alloc((size_t)NHEAD * 1024 * DIM * 2); // 32 MB
  float* part   = (float*)alloc((size_t)16 * NHEAD * N_PATCH * 4);              // 8 MB
  float* scores = (float*)alloc((size_t)NHEAD * N_PATCH * 4);
  float* stats  = (float*)alloc(NHEAD * 2 * 4);
  float* wp1    = (float*)alloc(64 * DIM * 4);
  float* wp2    = (float*)alloc(64 * DIM * 4);
  float* y1     = (float*)alloc(DIM * 4);
  float* mvec   = (float*)alloc(DIM * 4);
  float* h1     = (float*)alloc(HID * 4);
  float* aggr   = (float*)alloc(DIM * 4);
  float* c1     = (float*)alloc(1024 * 4);
  float* c2     = (float*)alloc(512 * 4);

  prep_kernel<<<4096, 256, 0, stream>>>(x, xb, Vw, Uw, Wpt);
  gemm_scores_kernel<<<2048, 512, 0, stream>>>(xb, Wpt, Vb, Ub, ww, part);
  scores_stats_kernel<<<16, 256, 0, stream>>>(part, scores, stats);
  weighted_part_kernel<<<dim3(4, 64), 256, 0, stream>>>(x, scores, stats, wp1, wp2);
  reduce_vec_kernel<<<4, 256, 0, stream>>>(wp1, wp2, y1, mvec);
  gemv_fused_kernel<<<8, 256, 0, stream>>>(mvec, pW1, pb1, nullptr, 1.f, 1, h1, DIM, HID);
  gemv_fused_kernel<<<16, 256, 0, stream>>>(h1, pW2, pb2, y1, 1.f / 17.f, 0, aggr, HID, DIM);
  gemv_fused_kernel<<<16, 256, 0, stream>>>(aggr, cW1, cb1, nullptr, 1.f, 1, c1, 1024, 1024);
  gemv_fused_kernel<<<8, 256, 0, stream>>>(c1, cW2, cb2, nullptr, 1.f, 1, c2, 1024, 512);
  c3_final_kernel<<<1, 256, 0, stream>>>(c2, cW3, cb3, cW4, cb4, out);
}

// Round 7
// 474.014 us; speedup vs baseline: 1.4079x; 1.1864x over previous
//
#include <hip/hip_runtime.h>
#include <stdint.h>

// Sizes (fixed by the problem)
#define N_PATCH 8192
#define DIM     1024
#define HID     512
#define NHEAD   16

using short8 = __attribute__((ext_vector_type(8))) short;
using f32x4  = __attribute__((ext_vector_type(4))) float;

#define VMC(n) asm volatile("s_waitcnt vmcnt(" #n ")" ::: "memory")
#define BAR()  __builtin_amdgcn_s_barrier()
#define LGKM0  do { asm volatile("s_waitcnt lgkmcnt(0)" ::: "memory"); \
                    __builtin_amdgcn_sched_barrier(0); } while (0)
#define LGKM8  asm volatile("s_waitcnt lgkmcnt(8)" ::: "memory")

__device__ __forceinline__ unsigned short f2bf(float f) {
  unsigned u = __float_as_uint(f);
  u = u + 0x7fffu + ((u >> 16) & 1u);   // round-to-nearest-even
  return (unsigned short)(u >> 16);
}

// global -> LDS direct copy, 16B per lane (CK addrspace-cast pattern)
__device__ __forceinline__ void gload_lds16(const void* g, void* l) {
  __builtin_amdgcn_global_load_lds(
      reinterpret_cast<const __attribute__((address_space(1))) void*>(
          reinterpret_cast<uintptr_t>(g)),
      reinterpret_cast<__attribute__((address_space(3))) void*>(
          reinterpret_cast<uintptr_t>(l)),
      16, 0, 0);
}

// ---------------- fused prep: x fp32->bf16 (blocks 0..2047) + weight pack (2048..4095) ----
// pack: Wpt[k][c][d] bf16, c = (h>>4)*32 + u*16 + (h&15), u=0:V 1:U
__global__ void prep_kernel(const float* __restrict__ x,
                            unsigned short* __restrict__ xb,
                            const float* __restrict__ Vw,
                            const float* __restrict__ Uw,
                            unsigned short* __restrict__ Wpt) {
  __shared__ unsigned short T[128][68];
  const int bid = blockIdx.x;
  const int t = threadIdx.x;
  if (bid < 2048) {
    const int total4 = (N_PATCH * DIM) / 4;
    for (int i = bid * 256 + t; i < total4; i += 2048 * 256) {
      float4 v = ((const float4*)x)[i];
      ushort4 o;
      o.x = f2bf(v.x); o.y = f2bf(v.y); o.z = f2bf(v.z); o.w = f2bf(v.w);
      ((ushort4*)xb)[i] = o;
    }
    return;
  }
  const int idx = bid - 2048;
  const int hc = idx & 7;          // h chunk of 64
  const int dc = (idx >> 3) & 15;  // d chunk of 64
  const int k  = idx >> 7;         // head
  const int d0 = dc * 64, h0 = hc * 64;
  const size_t base = (size_t)k * DIM * HID;
  for (int u = 0; u < 2; ++u) {
    const float* W = u ? Uw : Vw;
    #pragma unroll
    for (int i = 0; i < 16; ++i) {
      int ii = i * 256 + t;
      int dd = ii >> 6, hh = ii & 63;
      float v = W[base + (size_t)(d0 + dd) * HID + h0 + hh];
      int cl = ((hh >> 4) << 5) + (u << 4) + (hh & 15);
      T[cl][dd] = f2bf(v);
    }
  }
  __syncthreads();
  const size_t obase = ((size_t)k * 1024 + hc * 128) * DIM + d0;
  #pragma unroll
  for (int i = 0; i < 8; ++i) {
    int ii = i * 1024 + t * 4;
    int cl = ii >> 6, dd = ii & 63;
    ushort4 o;
    o.x = T[cl][dd]; o.y = T[cl][dd + 1]; o.z = T[cl][dd + 2]; o.w = T[cl][dd + 3];
    *(ushort4*)&Wpt[obase + (size_t)cl * DIM + dd] = o;
  }
}

// ---------------- main GEMM + gated epilogue -> score partials ----------------
// 256x256 tile, BK=64, 8 waves (2M x 4N), 16x16x32 MFMA, 3-bit XOR swizzle,
// m201-verbatim schedule: 4 phases/K-tile, 2 stage-loads/phase, explicit
// lgkmcnt(0)+sched_barrier after each barrier, vmcnt(6) once per K-tile.
__global__ __launch_bounds__(512, 2) void gemm_scores_kernel(
    const unsigned short* __restrict__ xb,
    const unsigned short* __restrict__ Wpt,
    const float* __restrict__ Vb, const float* __restrict__ Ub,
    const float* __restrict__ ww, float* __restrict__ part) {
  __shared__ unsigned short As[2][16384];   // 64 KB
  __shared__ unsigned short Bs[2][16384];   // 64 KB
  const int bid = blockIdx.x;
  const int ct = (bid & 7) * 8 + (bid >> 8);   // XCD-chunked: 8 col-panels per XCD
  const int mt = (bid >> 3) & 31;
  const int kh = ct >> 2, cb = ct & 3;
  const int tid = threadIdx.x;
  const int wv = tid >> 6, lane = tid & 63;
  const int wr = wv >> 2, wc = wv & 3;         // 2 x 4 wave grid
  const int l15 = lane & 15, l4 = lane >> 4;

  const unsigned short* Ab = xb + (size_t)mt * 256 * DIM;
  const unsigned short* Bb = Wpt + (size_t)ct * 256 * DIM;

  const f32x4 vzero = {0.f, 0.f, 0.f, 0.f};
  f32x4 acc[8][4];
  #pragma unroll
  for (int i = 0; i < 8; ++i)
    #pragma unroll
    for (int j = 0; j < 4; ++j) acc[i][j] = vzero;

  // ---- staging: chunk = 16KB, 2 x gload_lds16 per thread, linear LDS dest,
  //      inverse-swizzled global source (elem k ^= ((r>>1)&7)<<3) ----
  auto stageA = [&](int t, int mh) {
    const int buf = t & 1, db = t << 6;
    #pragma unroll
    for (int j = 0; j < 2; ++j) {
      const int r = j * 128 + mh * 64 + wv * 8 + (lane >> 3);
      const int ksrc = ((lane & 7) * 8) ^ (((r >> 1) & 7) << 3);
      char* lds = (char*)&As[buf][0] + j * 16384 + mh * 8192 + wv * 1024;
      gload_lds16(Ab + (size_t)r * DIM + db + ksrc, lds);
    }
  };
  auto stageB = [&](int t, int nh) {
    const int buf = t & 1, db = t << 6;
    #pragma unroll
    for (int j = 0; j < 2; ++j) {
      const int piece = j * 2 + wr;
      const int r = piece * 64 + nh * 32 + (wv & 3) * 8 + (lane >> 3);
      const int ksrc = ((lane & 7) * 8) ^ (((r >> 1) & 7) << 3);
      char* lds = (char*)&Bs[buf][0] + piece * 8192 + nh * 4096 + (wv & 3) * 1024;
      gload_lds16(Bb + (size_t)r * DIM + db + ksrc, lds);
    }
  };

  // ---- hoisted swizzled read addresses (per-lane constants) ----
  const int swz = ((l15 >> 1) & 7) << 4;       // byte bits 4-6
  const int kb0 = (l4 * 16) ^ swz;
  const int aB0 = wr * 16384 + l15 * 128 + kb0;
  const int aB1 = aB0 ^ 64;                    // ks=1 flips byte-bit 6
  const int bB0 = wc * 8192 + l15 * 128 + kb0;
  const int bB1 = bB0 ^ 64;

  short8 a[8], b0[4], b1[4];
  auto LDA = [&](int buf, int mh) {            // 8 x ds_read_b128
    const char* base = (const char*)&As[buf][0] + mh * 8192;
    #pragma unroll
    for (int f = 0; f < 4; ++f) {
      a[f * 2 + 0] = *(const short8*)(base + aB0 + f * 2048);
      a[f * 2 + 1] = *(const short8*)(base + aB1 + f * 2048);
    }
  };
  auto LDB0 = [&](int buf) {                   // nh=0 -> b0
    const char* base = (const char*)&Bs[buf][0];
    #pragma unroll
    for (int g = 0; g < 2; ++g) {
      b0[g * 2 + 0] = *(const short8*)(base + bB0 + g * 2048);
      b0[g * 2 + 1] = *(const short8*)(base + bB1 + g * 2048);
    }
  };
  auto LDB1 = [&](int buf) {                   // nh=1 -> b1
    const char* base = (const char*)&Bs[buf][0] + 4096;
    #pragma unroll
    for (int g = 0; g < 2; ++g) {
      b1[g * 2 + 0] = *(const short8*)(base + bB0 + g * 2048);
      b1[g * 2 + 1] = *(const short8*)(base + bB1 + g * 2048);
    }
  };
  auto MFMAQ0 = [&](int mh) {                  // 16 MFMA, nh=0 quadrant
    __builtin_amdgcn_s_setprio(1);
    #pragma unroll
    for (int ks = 0; ks < 2; ++ks)
      #pragma unroll
      for (int f = 0; f < 4; ++f)
        #pragma unroll
        for (int g = 0; g < 2; ++g)
          acc[mh * 4 + f][g] = __builtin_amdgcn_mfma_f32_16x16x32_bf16(
              a[f * 2 + ks], b0[g * 2 + ks], acc[mh * 4 + f][g], 0, 0, 0);
    __builtin_amdgcn_s_setprio(0);
  };
  auto MFMAQ1 = [&](int mh) {                  // 16 MFMA, nh=1 quadrant
    __builtin_amdgcn_s_setprio(1);
    #pragma unroll
    for (int ks = 0; ks < 2; ++ks)
      #pragma unroll
      for (int f = 0; f < 4; ++f)
        #pragma unroll
        for (int g = 0; g < 2; ++g)
          acc[mh * 4 + f][2 + g] = __builtin_amdgcn_mfma_f32_16x16x32_bf16(
              a[f * 2 + ks], b1[g * 2 + ks], acc[mh * 4 + f][2 + g], 0, 0, 0);
    __builtin_amdgcn_s_setprio(0);
  };

  // ---- prologue: tile0 full (8), then A0(1),B1(1),B0(1) (6); drain tile0 ----
  stageA(0, 0); stageA(0, 1); stageB(0, 0); stageB(0, 1);
  stageA(1, 0); stageB(1, 1); stageB(1, 0);
  VMC(6);
  BAR();

  // ---- main loop u=0..13: 4 phases, 2 stage-loads each ----
  // Stage map: ph0->A1(u+1)[buf^1], ph1->A0(u+2)[buf], ph2->B1(u+2), ph3->B0(u+2).
  // Last reads: A0,B0 ph0; B1 ph1; A1 ph2 -> every stage barrier-separated. 
  // FIFO at ph3(u): [A0(u+1),B1(u+1),B0(u+1),A1(u+1), A0(u+2),B1(u+2),B0(u+2)]=14;
  // VMC(6) drains all 8 loads of tile u+1, leaves 6 of u+2 in flight.
  for (int u = 0; u < 14; ++u) {
    const int buf = u & 1;
    // ph0: reads A0,B0 (12 reads); stage A1(u+1)
    LDA(buf, 0); LDB0(buf); stageA(u + 1, 1);
    LGKM8; BAR(); LGKM0; MFMAQ0(0); BAR();
    // ph1: reads B1 (4); stage A0(u+2)
    LDB1(buf); stageA(u + 2, 0);
    BAR(); LGKM0; MFMAQ1(0); BAR();
    // ph2: reads A1 (8); stage B1(u+2)
    LDA(buf, 1); stageB(u + 2, 1);
    BAR(); LGKM0; MFMAQ0(1); BAR();
    // ph3: no reads; stage B0(u+2)
    stageB(u + 2, 0);
    BAR(); MFMAQ1(1); VMC(6); BAR();
  }
  // ---- u=14 (buf 0): only A1(15) left to stage; full drain at end ----
  LDA(0, 0); LDB0(0); stageA(15, 1);
  LGKM8; BAR(); LGKM0; MFMAQ0(0); BAR();
  LDB1(0);
  BAR(); LGKM0; MFMAQ1(0); BAR();
  LDA(0, 1);
  BAR(); LGKM0; MFMAQ0(1); BAR();
  MFMAQ1(1); VMC(0); BAR();
  // ---- u=15 (buf 1): no staging ----
  LDA(1, 0); LDB0(1);
  BAR(); LGKM0; MFMAQ0(0); BAR();
  LDB1(1);
  BAR(); LGKM0; MFMAQ1(0); BAR();
  LDA(1, 1);
  BAR(); LGKM0; MFMAQ0(1); BAR();
  MFMAQ1(1);

  // ---- gated epilogue: tanh(AV+Vb)*sigmoid(AU+Ub)*ww, reduce 16 lanes ----
  float partial[8][4];
  #pragma unroll
  for (int f = 0; f < 8; ++f)
    #pragma unroll
    for (int r = 0; r < 4; ++r) partial[f][r] = 0.f;

  #pragma unroll
  for (int p = 0; p < 2; ++p) {
    const int hl = (cb * 8 + wc * 2 + p) * 16 + l15;   // head-local h
    const float vb  = Vb[kh * HID + hl];
    const float ub  = Ub[kh * HID + hl];
    const float wwv = ww[kh * HID + hl];
    #pragma unroll
    for (int f = 0; f < 8; ++f)
      #pragma unroll
      for (int r = 0; r < 4; ++r) {
        const float xv = acc[f][2 * p][r] + vb;
        const float e2 = __expf(2.f * xv);
        const float av = 1.f - 2.f / (e2 + 1.f);       // tanh
        const float xu = acc[f][2 * p + 1][r] + ub;
        const float au = 1.f / (1.f + __expf(-xu));    // sigmoid
        partial[f][r] += av * au * wwv;
      }
  }
  #pragma unroll
  for (int s = 1; s < 16; s <<= 1)
    #pragma unroll
    for (int f = 0; f < 8; ++f)
      #pragma unroll
      for (int r = 0; r < 4; ++r)
        partial[f][r] += __shfl_xor(partial[f][r], s, 64);

  if (l15 == 0) {
    const int j = cb * 4 + wc;   // 0..15 partial slot
    float* dst = part + ((size_t)j * NHEAD + kh) * N_PATCH;
    const int rbase = mt * 256 + wr * 128 + l4 * 4;
    #pragma unroll
    for (int f = 0; f < 8; ++f)
      #pragma unroll
      for (int r = 0; r < 4; ++r)
        dst[rbase + f * 16 + r] = partial[f][r];
  }
}

// ---------------- scores + per-chunk softmax partials (128 blocks) ----------------
__global__ void scores_part_kernel(const float* __restrict__ part,
                                   float* __restrict__ scores,
                                   float* __restrict__ spart) {
  const int k = blockIdx.x >> 3, c = blockIdx.x & 7;
  const int t = threadIdx.x;   // 256
  __shared__ float shm[4], shs[4];
  float v[4];
  float mx = -1e30f;
  #pragma unroll
  for (int i = 0; i < 4; ++i) {
    const int n = c * 1024 + i * 256 + t;
    float s = 0.f;
    #pragma unroll
    for (int j = 0; j < 16; ++j) s += part[((size_t)j * NHEAD + k) * N_PATCH + n];
    v[i] = s;
    scores[(size_t)k * N_PATCH + n] = s;
    mx = fmaxf(mx, s);
  }
  #pragma unroll
  for (int sft = 32; sft; sft >>= 1) mx = fmaxf(mx, __shfl_xor(mx, sft, 64));
  const int wv = t >> 6;
  if ((t & 63) == 0) shm[wv] = mx;
  __syncthreads();
  mx = fmaxf(fmaxf(shm[0], shm[1]), fmaxf(shm[2], shm[3]));
  float sum = 0.f;
  #pragma unroll
  for (int i = 0; i < 4; ++i) sum += __expf(v[i] - mx);
  #pragma unroll
  for (int sft = 32; sft; sft >>= 1) sum += __shfl_xor(sum, sft, 64);
  if ((t & 63) == 0) shs[wv] = sum;
  __syncthreads();
  if (t == 0) {
    spart[(k * 8 + c) * 2]     = mx;
    spart[(k * 8 + c) * 2 + 1] = shs[0] + shs[1] + shs[2] + shs[3];
  }
}

// ---------------- combine chunk stats -> per-head (max, sumexp) ----------------
__global__ void stats_combine_kernel(const float* __restrict__ spart,
                                     float* __restrict__ stats) {
  const int k = threadIdx.x;   // 64 threads, use 16
  if (k < NHEAD) {
    float m = -1e30f;
    #pragma unroll
    for (int c = 0; c < 8; ++c) m = fmaxf(m, spart[(k * 8 + c) * 2]);
    float S = 0.f;
    #pragma unroll
    for (int c = 0; c < 8; ++c)
      S += spart[(k * 8 + c) * 2 + 1] * __expf(spart[(k * 8 + c) * 2] - m);
    stats[2 * k] = m;
    stats[2 * k + 1] = S;
  }
}

// ---------------- fused: w[n]=sum_k softmax_k(n); wp1/wp2 partial sums over rows ----
__global__ void weighted_part_kernel(const float* __restrict__ x,
                                     const float* __restrict__ scores,
                                     const float* __restrict__ stats,
                                     float* __restrict__ wp1,
                                     float* __restrict__ wp2) {
  __shared__ float wrow[128];
  const int d = blockIdx.x * 256 + threadIdx.x;  // grid.x = 4
  const int nc = blockIdx.y;                     // 64 chunks of 128 rows
  if (threadIdx.x < 128) {
    const int n = nc * 128 + threadIdx.x;
    float s = 0.f;
    #pragma unroll
    for (int k = 0; k < NHEAD; ++k)
      s += __expf(scores[(size_t)k * N_PATCH + n] - stats[2 * k]) / stats[2 * k + 1];
    wrow[threadIdx.x] = s;
  }
  __syncthreads();
  float a1 = 0.f, a2 = 0.f;
  for (int i = 0; i < 128; ++i) {
    float xv = x[(size_t)(nc * 128 + i) * DIM + d];
    a1 += wrow[i] * xv;
    a2 += xv;
  }
  wp1[nc * DIM + d] = a1;
  wp2[nc * DIM + d] = a2;
}

__global__ void reduce_vec_kernel(const float* __restrict__ wp1,
                                  const float* __restrict__ wp2,
                                  float* __restrict__ y1,
                                  float* __restrict__ mvec) {
  int d = blockIdx.x * 256 + threadIdx.x;
  float s1 = 0.f, s2 = 0.f;
  #pragma unroll
  for (int i = 0; i < 64; ++i) {
    s1 += wp1[i * DIM + d];
    s2 += wp2[i * DIM + d];
  }
  y1[d] = s1;
  mvec[d] = s2 * (1.f / (float)N_PATCH);
}

// ---------------- one-dispatch GEMV: in-block split-K (4 kc x 64 j), LDS reduce ----
__global__ void gemv_fused_kernel(const float* __restrict__ in,
                                  const float* __restrict__ W,
                                  const float* __restrict__ bias,
                                  const float* __restrict__ extra, float scale,
                                  int do_relu, float* __restrict__ out,
                                  int In, int Out) {
  __shared__ float red[4][64];
  const int jl = threadIdx.x & 63, kc = threadIdx.x >> 6;
  const int j = blockIdx.x * 64 + jl;
  const int chunk = In >> 2;
  const float* Wp = W + (size_t)(kc * chunk) * Out + j;
  const float* ip = in + kc * chunk;
  float acc = 0.f;
  #pragma unroll 4
  for (int d = 0; d < chunk; ++d) acc += ip[d] * Wp[(size_t)d * Out];
  if (kc) red[kc][jl] = acc;
  __syncthreads();
  if (kc == 0) {
    float v = bias[j] + acc + red[1][jl] + red[2][jl] + red[3][jl];
    if (extra) v += extra[j];
    v *= scale;
    if (do_relu) v = fmaxf(v, 0.f);
    out[j] = v;
  }
}

// ---------------- fused: c3 = relu(c2@cW3+cb3); logits = c3@cW4+cb4; softmax ----
__global__ void c3_final_kernel(const float* __restrict__ c2,
                                const float* __restrict__ W3,
                                const float* __restrict__ b3,
                                const float* __restrict__ W4,
                                const float* __restrict__ b4,
                                float* __restrict__ out) {
  __shared__ float c3s[256];
  __shared__ float logits[9];
  const int t = threadIdx.x;   // 256
  float acc = b3[t];
  #pragma unroll 4
  for (int d = 0; d < 512; ++d) acc += c2[d] * W3[(size_t)d * 256 + t];
  c3s[t] = fmaxf(acc, 0.f);
  __syncthreads();
  if (t < 9) {
    float l = b4[t];
    for (int d = 0; d < 256; ++d) l += c3s[d] * W4[d * 9 + t];
    logits[t] = l;
  }
  __syncthreads();
  if (t == 0) {
    float mx = logits[0];
    for (int j = 1; j < 9; ++j) mx = fmaxf(mx, logits[j]);
    float e[9], s = 0.f;
    for (int j = 0; j < 9; ++j) { e[j] = expf(logits[j] - mx); s += e[j]; }
    for (int j = 0; j < 9; ++j) out[j] = e[j] / s;
  }
}

extern "C" void kernel_launch(void* const* d_in, const int* in_sizes, int n_in,
                              void* d_out, int out_size, void* d_ws, size_t ws_size,
                              hipStream_t stream) {
  (void)in_sizes; (void)n_in; (void)out_size; (void)ws_size;
  const float* x   = (const float*)d_in[0];
  const float* Vw  = (const float*)d_in[1];
  const float* Vb  = (const float*)d_in[2];
  const float* Uw  = (const float*)d_in[3];
  const float* Ub  = (const float*)d_in[4];
  const float* ww  = (const float*)d_in[5];
  // d_in[6] = wb: constant per head -> softmax invariant -> unused
  const float* pW1 = (const float*)d_in[7];
  const float* pb1 = (const float*)d_in[8];
  const float* pW2 = (const float*)d_in[9];
  const float* pb2 = (const float*)d_in[10];
  const float* cW1 = (const float*)d_in[11];
  const float* cb1 = (const float*)d_in[12];
  const float* cW2 = (const float*)d_in[13];
  const float* cb2 = (const float*)d_in[14];
  const float* cW3 = (const float*)d_in[15];
  const float* cb3 = (const float*)d_in[16];
  const float* cW4 = (const float*)d_in[17];
  const float* cb4 = (const float*)d_in[18];
  float* out = (float*)d_out;

  char* ws = (char*)d_ws;
  size_t o = 0;
  auto alloc = [&](size_t bytes) -> char* {
    char* p = ws + o;
    o += (bytes + 255) & ~(size_t)255;
    return p;
  };
  unsigned short* xb  = (unsigned short*)alloc((size_t)N_PATCH * DIM * 2);      // 16 MB
  unsigned short* Wpt = (unsigned short*)alloc((size_t)NHEAD * 1024 * DIM * 2); // 32 MB
  float* part   = (float*)alloc((size_t)16 * NHEAD * N_PATCH * 4);              // 8 MB
  float* scores = (float*)alloc((size_t)NHEAD * N_PATCH * 4);
  float* spart  = (float*)alloc(NHEAD * 8 * 2 * 4);
  float* stats  = (float*)alloc(NHEAD * 2 * 4);
  float* wp1    = (float*)alloc(64 * DIM * 4);
  float* wp2    = (float*)alloc(64 * DIM * 4);
  float* y1     = (float*)alloc(DIM * 4);
  float* mvec   = (float*)alloc(DIM * 4);
  float* h1     = (float*)alloc(HID * 4);
  float* aggr   = (float*)alloc(DIM * 4);
  float* c1     = (float*)alloc(1024 * 4);
  float* c2     = (float*)alloc(512 * 4);

  prep_kernel<<<4096, 256, 0, stream>>>(x, xb, Vw, Uw, Wpt);
  gemm_scores_kernel<<<2048, 512, 0, stream>>>(xb, Wpt, Vb, Ub, ww, part);
  scores_part_kernel<<<128, 256, 0, stream>>>(part, scores, spart);
  stats_combine_kernel<<<1, 64, 0, stream>>>(spart, stats);
  weighted_part_kernel<<<dim3(4, 64), 256, 0, stream>>>(x, scores, stats, wp1, wp2);
  reduce_vec_kernel<<<4, 256, 0, stream>>>(wp1, wp2, y1, mvec);
  gemv_fused_kernel<<<8, 256, 0, stream>>>(mvec, pW1, pb1, nullptr, 1.f, 1, h1, DIM, HID);
  gemv_fused_kernel<<<16, 256, 0, stream>>>(h1, pW2, pb2, y1, 1.f / 17.f, 0, aggr, HID, DIM);
  gemv_fused_kernel<<<16, 256, 0, stream>>>(aggr, cW1, cb1, nullptr, 1.f, 1, c1, 1024, 1024);
  gemv_fused_kernel<<<8, 256, 0, stream>>>(c1, cW2, cb2, nullptr, 1.f, 1, c2, 1024, 512);
  c3_final_kernel<<<1, 256, 0, stream>>>(c2, cW3, cb3, cW4, cb4, out);
}

// Round 8
// 469.623 us; speedup vs baseline: 1.4210x; 1.0093x over previous
//
#include <hip/hip_runtime.h>
#include <stdint.h>

// Sizes (fixed by the problem)
#define N_PATCH 8192
#define DIM     1024
#define HID     512
#define NHEAD   16

using short8 = __attribute__((ext_vector_type(8))) short;
using f32x4  = __attribute__((ext_vector_type(4))) float;

__device__ __forceinline__ unsigned short f2bf(float f) {
  unsigned u = __float_as_uint(f);
  u = u + 0x7fffu + ((u >> 16) & 1u);   // round-to-nearest-even
  return (unsigned short)(u >> 16);
}

// global -> LDS direct copy, 16B per lane (CK addrspace-cast pattern)
__device__ __forceinline__ void gload_lds16(const void* g, void* l) {
  __builtin_amdgcn_global_load_lds(
      reinterpret_cast<const __attribute__((address_space(1))) void*>(
          reinterpret_cast<uintptr_t>(g)),
      reinterpret_cast<__attribute__((address_space(3))) void*>(
          reinterpret_cast<uintptr_t>(l)),
      16, 0, 0);
}

// ---------------- fused prep: x fp32->bf16 (blocks 0..2047) + weight pack (2048..4095) ----
// pack: Wpt[k][c][d] bf16, c = (h>>4)*32 + u*16 + (h&15), u=0:V 1:U
__global__ void prep_kernel(const float* __restrict__ x,
                            unsigned short* __restrict__ xb,
                            const float* __restrict__ Vw,
                            const float* __restrict__ Uw,
                            unsigned short* __restrict__ Wpt) {
  __shared__ unsigned short T[128][68];
  const int bid = blockIdx.x;
  const int t = threadIdx.x;
  if (bid < 2048) {
    const int total4 = (N_PATCH * DIM) / 4;
    for (int i = bid * 256 + t; i < total4; i += 2048 * 256) {
      float4 v = ((const float4*)x)[i];
      ushort4 o;
      o.x = f2bf(v.x); o.y = f2bf(v.y); o.z = f2bf(v.z); o.w = f2bf(v.w);
      ((ushort4*)xb)[i] = o;
    }
    return;
  }
  const int idx = bid - 2048;
  const int hc = idx & 7;          // h chunk of 64
  const int dc = (idx >> 3) & 15;  // d chunk of 64
  const int k  = idx >> 7;         // head
  const int d0 = dc * 64, h0 = hc * 64;
  const size_t base = (size_t)k * DIM * HID;
  for (int u = 0; u < 2; ++u) {
    const float* W = u ? Uw : Vw;
    #pragma unroll
    for (int i = 0; i < 16; ++i) {
      int ii = i * 256 + t;
      int dd = ii >> 6, hh = ii & 63;
      float v = W[base + (size_t)(d0 + dd) * HID + h0 + hh];
      int cl = ((hh >> 4) << 5) + (u << 4) + (hh & 15);
      T[cl][dd] = f2bf(v);
    }
  }
  __syncthreads();
  const size_t obase = ((size_t)k * 1024 + hc * 128) * DIM + d0;
  #pragma unroll
  for (int i = 0; i < 8; ++i) {
    int ii = i * 1024 + t * 4;
    int cl = ii >> 6, dd = ii & 63;
    ushort4 o;
    o.x = T[cl][dd]; o.y = T[cl][dd + 1]; o.z = T[cl][dd + 2]; o.w = T[cl][dd + 3];
    *(ushort4*)&Wpt[obase + (size_t)cl * DIM + dd] = o;
  }
}

// ---------------- main GEMM + gated epilogue -> score partials ----------------
// 256x256 tile, BK=64, 8 waves (2M x 4N), 16x16x32 MFMA, 3-bit XOR swizzle,
// ONE __syncthreads per K-tile: whole tile body (24 ds_reads + 8 stage-gloads
// + 64 MFMA) is a single compiler-scheduled region; waves may skew -> DS||MFMA.
__global__ __launch_bounds__(512, 1) void gemm_scores_kernel(
    const unsigned short* __restrict__ xb,
    const unsigned short* __restrict__ Wpt,
    const float* __restrict__ Vb, const float* __restrict__ Ub,
    const float* __restrict__ ww, float* __restrict__ part) {
  __shared__ unsigned short As[2][16384];   // 64 KB
  __shared__ unsigned short Bs[2][16384];   // 64 KB
  const int bid = blockIdx.x;
  const int ct = (bid & 7) * 8 + (bid >> 8);   // XCD-chunked: 8 col-panels per XCD
  const int mt = (bid >> 3) & 31;
  const int kh = ct >> 2, cb = ct & 3;
  const int tid = threadIdx.x;
  const int wv = tid >> 6, lane = tid & 63;
  const int wr = wv >> 2, wc = wv & 3;         // 2 x 4 wave grid
  const int l15 = lane & 15, l4 = lane >> 4;

  const unsigned short* Ab = xb + (size_t)mt * 256 * DIM;
  const unsigned short* Bb = Wpt + (size_t)ct * 256 * DIM;

  const f32x4 vzero = {0.f, 0.f, 0.f, 0.f};
  f32x4 acc[8][4];
  #pragma unroll
  for (int i = 0; i < 8; ++i)
    #pragma unroll
    for (int j = 0; j < 4; ++j) acc[i][j] = vzero;

  // ---- staging: chunk = 16KB, 2 x gload_lds16 per thread, linear LDS dest,
  //      inverse-swizzled global source (elem k ^= ((r>>1)&7)<<3) ----
  auto stageA = [&](int t, int mh) {
    const int buf = t & 1, db = t << 6;
    #pragma unroll
    for (int j = 0; j < 2; ++j) {
      const int r = j * 128 + mh * 64 + wv * 8 + (lane >> 3);
      const int ksrc = ((lane & 7) * 8) ^ (((r >> 1) & 7) << 3);
      char* lds = (char*)&As[buf][0] + j * 16384 + mh * 8192 + wv * 1024;
      gload_lds16(Ab + (size_t)r * DIM + db + ksrc, lds);
    }
  };
  auto stageB = [&](int t, int nh) {
    const int buf = t & 1, db = t << 6;
    #pragma unroll
    for (int j = 0; j < 2; ++j) {
      const int piece = j * 2 + wr;
      const int r = piece * 64 + nh * 32 + (wv & 3) * 8 + (lane >> 3);
      const int ksrc = ((lane & 7) * 8) ^ (((r >> 1) & 7) << 3);
      char* lds = (char*)&Bs[buf][0] + piece * 8192 + nh * 4096 + (wv & 3) * 1024;
      gload_lds16(Bb + (size_t)r * DIM + db + ksrc, lds);
    }
  };

  // ---- hoisted swizzled read addresses (per-lane constants) ----
  const int swz = ((l15 >> 1) & 7) << 4;       // byte bits 4-6
  const int kb0 = (l4 * 16) ^ swz;
  const int aB0 = wr * 16384 + l15 * 128 + kb0;
  const int aB1 = aB0 ^ 64;                    // ks=1 flips byte-bit 6
  const int bB0 = wc * 8192 + l15 * 128 + kb0;
  const int bB1 = bB0 ^ 64;

  short8 a0[8], a1[8], b0[4], b1[4];
  auto LDA0 = [&](int buf) {                   // mh=0: 8 x ds_read_b128
    const char* base = (const char*)&As[buf][0];
    #pragma unroll
    for (int f = 0; f < 4; ++f) {
      a0[f * 2 + 0] = *(const short8*)(base + aB0 + f * 2048);
      a0[f * 2 + 1] = *(const short8*)(base + aB1 + f * 2048);
    }
  };
  auto LDA1 = [&](int buf) {                   // mh=1: 8 x ds_read_b128
    const char* base = (const char*)&As[buf][0] + 8192;
    #pragma unroll
    for (int f = 0; f < 4; ++f) {
      a1[f * 2 + 0] = *(const short8*)(base + aB0 + f * 2048);
      a1[f * 2 + 1] = *(const short8*)(base + aB1 + f * 2048);
    }
  };
  auto LDB0 = [&](int buf) {
    const char* base = (const char*)&Bs[buf][0];
    #pragma unroll
    for (int g = 0; g < 2; ++g) {
      b0[g * 2 + 0] = *(const short8*)(base + bB0 + g * 2048);
      b0[g * 2 + 1] = *(const short8*)(base + bB1 + g * 2048);
    }
  };
  auto LDB1 = [&](int buf) {
    const char* base = (const char*)&Bs[buf][0] + 4096;
    #pragma unroll
    for (int g = 0; g < 2; ++g) {
      b1[g * 2 + 0] = *(const short8*)(base + bB0 + g * 2048);
      b1[g * 2 + 1] = *(const short8*)(base + bB1 + g * 2048);
    }
  };

  // ---- prologue: stage tiles 0 and 1; one conservative drain ----
  stageA(0, 0); stageA(0, 1); stageB(0, 0); stageB(0, 1);
  stageA(1, 0); stageA(1, 1); stageB(1, 0); stageB(1, 1);
  __syncthreads();   // vmcnt(0) + barrier: both tiles resident

  // ---- main loop: one barrier per K-tile; compiler schedules the region ----
  // Reads tile u from buf; stages tile u+1 into buf^1 (disjoint). Every ds_read
  // is consumed by an MFMA (compiler inserts counted lgkm waits), so at the
  // barrier all reads are retired; syncthreads' vmcnt(0) drains the stage.
  for (int u = 0; u < 16; ++u) {
    const int buf = u & 1;
    // first half of reads
    LDA0(buf); LDB0(buf); LDB1(buf);
    // stage next tile into the other buffer (skip on last)
    if (u < 15) { stageA(u + 1, 0); stageA(u + 1, 1); stageB(u + 1, 0); stageB(u + 1, 1); }
    // quadrant (mh0, nh0) + (mh0, nh1)
    #pragma unroll
    for (int ks = 0; ks < 2; ++ks)
      #pragma unroll
      for (int f = 0; f < 4; ++f)
        #pragma unroll
        for (int g = 0; g < 2; ++g)
          acc[f][g] = __builtin_amdgcn_mfma_f32_16x16x32_bf16(
              a0[f * 2 + ks], b0[g * 2 + ks], acc[f][g], 0, 0, 0);
    // second half of reads (overlaps MFMA above in DS pipe)
    LDA1(buf);
    #pragma unroll
    for (int ks = 0; ks < 2; ++ks)
      #pragma unroll
      for (int f = 0; f < 4; ++f)
        #pragma unroll
        for (int g = 0; g < 2; ++g)
          acc[f][2 + g] = __builtin_amdgcn_mfma_f32_16x16x32_bf16(
              a0[f * 2 + ks], b1[g * 2 + ks], acc[f][2 + g], 0, 0, 0);
    #pragma unroll
    for (int ks = 0; ks < 2; ++ks)
      #pragma unroll
      for (int f = 0; f < 4; ++f) {
        #pragma unroll
        for (int g = 0; g < 2; ++g)
          acc[4 + f][g] = __builtin_amdgcn_mfma_f32_16x16x32_bf16(
              a1[f * 2 + ks], b0[g * 2 + ks], acc[4 + f][g], 0, 0, 0);
        #pragma unroll
        for (int g = 0; g < 2; ++g)
          acc[4 + f][2 + g] = __builtin_amdgcn_mfma_f32_16x16x32_bf16(
              a1[f * 2 + ks], b1[g * 2 + ks], acc[4 + f][2 + g], 0, 0, 0);
      }
    __syncthreads();   // vmcnt(0) (stage u+1 resident) + read-retire fence
  }

  // ---- gated epilogue: tanh(AV+Vb)*sigmoid(AU+Ub)*ww, reduce 16 lanes ----
  float partial[8][4];
  #pragma unroll
  for (int f = 0; f < 8; ++f)
    #pragma unroll
    for (int r = 0; r < 4; ++r) partial[f][r] = 0.f;

  #pragma unroll
  for (int p = 0; p < 2; ++p) {
    const int hl = (cb * 8 + wc * 2 + p) * 16 + l15;   // head-local h
    const float vb  = Vb[kh * HID + hl];
    const float ub  = Ub[kh * HID + hl];
    const float wwv = ww[kh * HID + hl];
    #pragma unroll
    for (int f = 0; f < 8; ++f)
      #pragma unroll
      for (int r = 0; r < 4; ++r) {
        const float xv = acc[f][2 * p][r] + vb;
        const float e2 = __expf(2.f * xv);
        const float av = 1.f - 2.f / (e2 + 1.f);       // tanh
        const float xu = acc[f][2 * p + 1][r] + ub;
        const float au = 1.f / (1.f + __expf(-xu));    // sigmoid
        partial[f][r] += av * au * wwv;
      }
  }
  #pragma unroll
  for (int s = 1; s < 16; s <<= 1)
    #pragma unroll
    for (int f = 0; f < 8; ++f)
      #pragma unroll
      for (int r = 0; r < 4; ++r)
        partial[f][r] += __shfl_xor(partial[f][r], s, 64);

  if (l15 == 0) {
    const int j = cb * 4 + wc;   // 0..15 partial slot
    float* dst = part + ((size_t)j * NHEAD + kh) * N_PATCH;
    const int rbase = mt * 256 + wr * 128 + l4 * 4;
    #pragma unroll
    for (int f = 0; f < 8; ++f)
      #pragma unroll
      for (int r = 0; r < 4; ++r)
        dst[rbase + f * 16 + r] = partial[f][r];
  }
}

// ---------------- scores + per-chunk softmax partials (128 blocks) ----------------
__global__ void scores_part_kernel(const float* __restrict__ part,
                                   float* __restrict__ scores,
                                   float* __restrict__ spart) {
  const int k = blockIdx.x >> 3, c = blockIdx.x & 7;
  const int t = threadIdx.x;   // 256
  __shared__ float shm[4], shs[4];
  float v[4];
  float mx = -1e30f;
  #pragma unroll
  for (int i = 0; i < 4; ++i) {
    const int n = c * 1024 + i * 256 + t;
    float s = 0.f;
    #pragma unroll
    for (int j = 0; j < 16; ++j) s += part[((size_t)j * NHEAD + k) * N_PATCH + n];
    v[i] = s;
    scores[(size_t)k * N_PATCH + n] = s;
    mx = fmaxf(mx, s);
  }
  #pragma unroll
  for (int sft = 32; sft; sft >>= 1) mx = fmaxf(mx, __shfl_xor(mx, sft, 64));
  const int wv = t >> 6;
  if ((t & 63) == 0) shm[wv] = mx;
  __syncthreads();
  mx = fmaxf(fmaxf(shm[0], shm[1]), fmaxf(shm[2], shm[3]));
  float sum = 0.f;
  #pragma unroll
  for (int i = 0; i < 4; ++i) sum += __expf(v[i] - mx);
  #pragma unroll
  for (int sft = 32; sft; sft >>= 1) sum += __shfl_xor(sum, sft, 64);
  if ((t & 63) == 0) shs[wv] = sum;
  __syncthreads();
  if (t == 0) {
    spart[(k * 8 + c) * 2]     = mx;
    spart[(k * 8 + c) * 2 + 1] = shs[0] + shs[1] + shs[2] + shs[3];
  }
}

// ---------------- combine chunk stats -> per-head (max, sumexp) ----------------
__global__ void stats_combine_kernel(const float* __restrict__ spart,
                                     float* __restrict__ stats) {
  const int k = threadIdx.x;   // 64 threads, use 16
  if (k < NHEAD) {
    float m = -1e30f;
    #pragma unroll
    for (int c = 0; c < 8; ++c) m = fmaxf(m, spart[(k * 8 + c) * 2]);
    float S = 0.f;
    #pragma unroll
    for (int c = 0; c < 8; ++c)
      S += spart[(k * 8 + c) * 2 + 1] * __expf(spart[(k * 8 + c) * 2] - m);
    stats[2 * k] = m;
    stats[2 * k + 1] = S;
  }
}

// ---------------- fused: w[n]=sum_k softmax_k(n); wp1/wp2 partial sums over rows ----
__global__ void weighted_part_kernel(const float* __restrict__ x,
                                     const float* __restrict__ scores,
                                     const float* __restrict__ stats,
                                     float* __restrict__ wp1,
                                     float* __restrict__ wp2) {
  __shared__ float wrow[128];
  const int d = blockIdx.x * 256 + threadIdx.x;  // grid.x = 4
  const int nc = blockIdx.y;                     // 64 chunks of 128 rows
  if (threadIdx.x < 128) {
    const int n = nc * 128 + threadIdx.x;
    float s = 0.f;
    #pragma unroll
    for (int k = 0; k < NHEAD; ++k)
      s += __expf(scores[(size_t)k * N_PATCH + n] - stats[2 * k]) / stats[2 * k + 1];
    wrow[threadIdx.x] = s;
  }
  __syncthreads();
  float a1 = 0.f, a2 = 0.f;
  for (int i = 0; i < 128; ++i) {
    float xv = x[(size_t)(nc * 128 + i) * DIM + d];
    a1 += wrow[i] * xv;
    a2 += xv;
  }
  wp1[nc * DIM + d] = a1;
  wp2[nc * DIM + d] = a2;
}

__global__ void reduce_vec_kernel(const float* __restrict__ wp1,
                                  const float* __restrict__ wp2,
                                  float* __restrict__ y1,
                                  float* __restrict__ mvec) {
  int d = blockIdx.x * 256 + threadIdx.x;
  float s1 = 0.f, s2 = 0.f;
  #pragma unroll
  for (int i = 0; i < 64; ++i) {
    s1 += wp1[i * DIM + d];
    s2 += wp2[i * DIM + d];
  }
  y1[d] = s1;
  mvec[d] = s2 * (1.f / (float)N_PATCH);
}

// ---------------- one-dispatch GEMV: in-block split-K (4 kc x 64 j), LDS reduce ----
__global__ void gemv_fused_kernel(const float* __restrict__ in,
                                  const float* __restrict__ W,
                                  const float* __restrict__ bias,
                                  const float* __restrict__ extra, float scale,
                                  int do_relu, float* __restrict__ out,
                                  int In, int Out) {
  __shared__ float red[4][64];
  const int jl = threadIdx.x & 63, kc = threadIdx.x >> 6;
  const int j = blockIdx.x * 64 + jl;
  const int chunk = In >> 2;
  const float* Wp = W + (size_t)(kc * chunk) * Out + j;
  const float* ip = in + kc * chunk;
  float acc = 0.f;
  #pragma unroll 4
  for (int d = 0; d < chunk; ++d) acc += ip[d] * Wp[(size_t)d * Out];
  if (kc) red[kc][jl] = acc;
  __syncthreads();
  if (kc == 0) {
    float v = bias[j] + acc + red[1][jl] + red[2][jl] + red[3][jl];
    if (extra) v += extra[j];
    v *= scale;
    if (do_relu) v = fmaxf(v, 0.f);
    out[j] = v;
  }
}

// ---------------- fused: c3 = relu(c2@cW3+cb3); logits = c3@cW4+cb4; softmax ----
__global__ void c3_final_kernel(const float* __restrict__ c2,
                                const float* __restrict__ W3,
                                const float* __restrict__ b3,
                                const float* __restrict__ W4,
                                const float* __restrict__ b4,
                                float* __restrict__ out) {
  __shared__ float c3s[256];
  __shared__ float logits[9];
  const int t = threadIdx.x;   // 256
  float acc = b3[t];
  #pragma unroll 4
  for (int d = 0; d < 512; ++d) acc += c2[d] * W3[(size_t)d * 256 + t];
  c3s[t] = fmaxf(acc, 0.f);
  __syncthreads();
  if (t < 9) {
    float l = b4[t];
    for (int d = 0; d < 256; ++d) l += c3s[d] * W4[d * 9 + t];
    logits[t] = l;
  }
  __syncthreads();
  if (t == 0) {
    float mx = logits[0];
    for (int j = 1; j < 9; ++j) mx = fmaxf(mx, logits[j]);
    float e[9], s = 0.f;
    for (int j = 0; j < 9; ++j) { e[j] = expf(logits[j] - mx); s += e[j]; }
    for (int j = 0; j < 9; ++j) out[j] = e[j] / s;
  }
}

extern "C" void kernel_launch(void* const* d_in, const int* in_sizes, int n_in,
                              void* d_out, int out_size, void* d_ws, size_t ws_size,
                              hipStream_t stream) {
  (void)in_sizes; (void)n_in; (void)out_size; (void)ws_size;
  const float* x   = (const float*)d_in[0];
  const float* Vw  = (const float*)d_in[1];
  const float* Vb  = (const float*)d_in[2];
  const float* Uw  = (const float*)d_in[3];
  const float* Ub  = (const float*)d_in[4];
  const float* ww  = (const float*)d_in[5];
  // d_in[6] = wb: constant per head -> softmax invariant -> unused
  const float* pW1 = (const float*)d_in[7];
  const float* pb1 = (const float*)d_in[8];
  const float* pW2 = (const float*)d_in[9];
  const float* pb2 = (const float*)d_in[10];
  const float* cW1 = (const float*)d_in[11];
  const float* cb1 = (const float*)d_in[12];
  const float* cW2 = (const float*)d_in[13];
  const float* cb2 = (const float*)d_in[14];
  const float* cW3 = (const float*)d_in[15];
  const float* cb3 = (const float*)d_in[16];
  const float* cW4 = (const float*)d_in[17];
  const float* cb4 = (const float*)d_in[18];
  float* out = (float*)d_out;

  char* ws = (char*)d_ws;
  size_t o = 0;
  auto alloc = [&](size_t bytes) -> char* {
    char* p = ws + o;
    o += (bytes + 255) & ~(size_t)255;
    return p;
  };
  unsigned short* xb  = (unsigned short*)alloc((size_t)N_PATCH * DIM * 2);      // 16 MB
  unsigned short* Wpt = (unsigned short*)alloc((size_t)NHEAD * 1024 * DIM * 2); // 32 MB
  float* part   = (float*)alloc((size_t)16 * NHEAD * N_PATCH * 4);              // 8 MB
  float* scores = (float*)alloc((size_t)NHEAD * N_PATCH * 4);
  float* spart  = (float*)alloc(NHEAD * 8 * 2 * 4);
  float* stats  = (float*)alloc(NHEAD * 2 * 4);
  float* wp1    = (float*)alloc(64 * DIM * 4);
  float* wp2    = (float*)alloc(64 * DIM * 4);
  float* y1     = (float*)alloc(DIM * 4);
  float* mvec   = (float*)alloc(DIM * 4);
  float* h1     = (float*)alloc(HID * 4);
  float* aggr   = (float*)alloc(DIM * 4);
  float* c1     = (float*)alloc(1024 * 4);
  float* c2     = (float*)alloc(512 * 4);

  prep_kernel<<<4096, 256, 0, stream>>>(x, xb, Vw, Uw, Wpt);
  gemm_scores_kernel<<<2048, 512, 0, stream>>>(xb, Wpt, Vb, Ub, ww, part);
  scores_part_kernel<<<128, 256, 0, stream>>>(part, scores, spart);
  stats_combine_kernel<<<1, 64, 0, stream>>>(spart, stats);
  weighted_part_kernel<<<dim3(4, 64), 256, 0, stream>>>(x, scores, stats, wp1, wp2);
  reduce_vec_kernel<<<4, 256, 0, stream>>>(wp1, wp2, y1, mvec);
  gemv_fused_kernel<<<8, 256, 0, stream>>>(mvec, pW1, pb1, nullptr, 1.f, 1, h1, DIM, HID);
  gemv_fused_kernel<<<16, 256, 0, stream>>>(h1, pW2, pb2, y1, 1.f / 17.f, 0, aggr, HID, DIM);
  gemv_fused_kernel<<<16, 256, 0, stream>>>(aggr, cW1, cb1, nullptr, 1.f, 1, c1, 1024, 1024);
  gemv_fused_kernel<<<8, 256, 0, stream>>>(c1, cW2, cb2, nullptr, 1.f, 1, c2, 1024, 512);
  c3_final_kernel<<<1, 256, 0, stream>>>(c2, cW3, cb3, cW4, cb4, out);
}

// Round 9
// 456.973 us; speedup vs baseline: 1.4604x; 1.0277x over previous
//
#include <hip/hip_runtime.h>
#include <stdint.h>

// Sizes (fixed by the problem)
#define N_PATCH 8192
#define DIM     1024
#define HID     512
#define NHEAD   16

using short8 = __attribute__((ext_vector_type(8))) short;
using f32x4  = __attribute__((ext_vector_type(4))) float;

__device__ __forceinline__ unsigned short f2bf(float f) {
  unsigned u = __float_as_uint(f);
  u = u + 0x7fffu + ((u >> 16) & 1u);   // round-to-nearest-even
  return (unsigned short)(u >> 16);
}

// global -> LDS direct copy, 16B per lane (CK addrspace-cast pattern)
__device__ __forceinline__ void gload_lds16(const void* g, void* l) {
  __builtin_amdgcn_global_load_lds(
      reinterpret_cast<const __attribute__((address_space(1))) void*>(
          reinterpret_cast<uintptr_t>(g)),
      reinterpret_cast<__attribute__((address_space(3))) void*>(
          reinterpret_cast<uintptr_t>(l)),
      16, 0, 0);
}

// ---------------- fused prep: x fp32->bf16 (blocks 0..2047) + weight pack (2048..4095) ----
// pack: Wpt[k][c][d] bf16, c = (h>>4)*32 + u*16 + (h&15), u=0:V 1:U
__global__ void prep_kernel(const float* __restrict__ x,
                            unsigned short* __restrict__ xb,
                            const float* __restrict__ Vw,
                            const float* __restrict__ Uw,
                            unsigned short* __restrict__ Wpt) {
  __shared__ unsigned short T[128][68];
  const int bid = blockIdx.x;
  const int t = threadIdx.x;
  if (bid < 2048) {
    const int total4 = (N_PATCH * DIM) / 4;
    for (int i = bid * 256 + t; i < total4; i += 2048 * 256) {
      float4 v = ((const float4*)x)[i];
      ushort4 o;
      o.x = f2bf(v.x); o.y = f2bf(v.y); o.z = f2bf(v.z); o.w = f2bf(v.w);
      ((ushort4*)xb)[i] = o;
    }
    return;
  }
  const int idx = bid - 2048;
  const int hc = idx & 7;          // h chunk of 64
  const int dc = (idx >> 3) & 15;  // d chunk of 64
  const int k  = idx >> 7;         // head
  const int d0 = dc * 64, h0 = hc * 64;
  const size_t base = (size_t)k * DIM * HID;
  for (int u = 0; u < 2; ++u) {
    const float* W = u ? Uw : Vw;
    #pragma unroll
    for (int i = 0; i < 16; ++i) {
      int ii = i * 256 + t;
      int dd = ii >> 6, hh = ii & 63;
      float v = W[base + (size_t)(d0 + dd) * HID + h0 + hh];
      int cl = ((hh >> 4) << 5) + (u << 4) + (hh & 15);
      T[cl][dd] = f2bf(v);
    }
  }
  __syncthreads();
  const size_t obase = ((size_t)k * 1024 + hc * 128) * DIM + d0;
  #pragma unroll
  for (int i = 0; i < 8; ++i) {
    int ii = i * 1024 + t * 4;
    int cl = ii >> 6, dd = ii & 63;
    ushort4 o;
    o.x = T[cl][dd]; o.y = T[cl][dd + 1]; o.z = T[cl][dd + 2]; o.w = T[cl][dd + 3];
    *(ushort4*)&Wpt[obase + (size_t)cl * DIM + dd] = o;
  }
}

// ---------------- main GEMM + gated epilogue -> score partials ----------------
// 256x256 tile, BK=64, 8 waves (2M x 4N), 16x16x32 MFMA, 3-bit XOR swizzle,
// one __syncthreads per K-tile (wave-skew overlap), L2-aware 2D block map:
// each XCD owns a 16mt x 16ct rectangle; concurrent window = 8mt x 4ct (6MB).
__global__ __launch_bounds__(512, 1) void gemm_scores_kernel(
    const unsigned short* __restrict__ xb,
    const unsigned short* __restrict__ Wpt,
    const float* __restrict__ Vb, const float* __restrict__ Ub,
    const float* __restrict__ ww, float* __restrict__ part) {
  __shared__ unsigned short As[2][16384];   // 64 KB
  __shared__ unsigned short Bs[2][16384];   // 64 KB
  const int bid = blockIdx.x;
  const int x8 = bid & 7;           // XCD (round-robin dispatch assumption)
  const int s  = (bid >> 3) & 31;   // concurrent window slot within XCD
  const int w  = bid >> 8;          // epoch 0..7
  const int mt = (x8 & 1) * 16 + (w & 1) * 8 + (s >> 2);   // 0..31
  const int ct = (x8 >> 1) * 16 + (w >> 1) * 4 + (s & 3);  // 0..63
  const int kh = ct >> 2, cb = ct & 3;
  const int tid = threadIdx.x;
  const int wv = tid >> 6, lane = tid & 63;
  const int wr = wv >> 2, wc = wv & 3;         // 2 x 4 wave grid
  const int l15 = lane & 15, l4 = lane >> 4;

  const unsigned short* Ab = xb + (size_t)mt * 256 * DIM;
  const unsigned short* Bb = Wpt + (size_t)ct * 256 * DIM;

  const f32x4 vzero = {0.f, 0.f, 0.f, 0.f};
  f32x4 acc[8][4];
  #pragma unroll
  for (int i = 0; i < 8; ++i)
    #pragma unroll
    for (int j = 0; j < 4; ++j) acc[i][j] = vzero;

  // ---- staging: chunk = 16KB, 2 x gload_lds16 per thread, linear LDS dest,
  //      inverse-swizzled global source (elem k ^= ((r>>1)&7)<<3) ----
  auto stageA = [&](int t, int mh) {
    const int buf = t & 1, db = t << 6;
    #pragma unroll
    for (int j = 0; j < 2; ++j) {
      const int r = j * 128 + mh * 64 + wv * 8 + (lane >> 3);
      const int ksrc = ((lane & 7) * 8) ^ (((r >> 1) & 7) << 3);
      char* lds = (char*)&As[buf][0] + j * 16384 + mh * 8192 + wv * 1024;
      gload_lds16(Ab + (size_t)r * DIM + db + ksrc, lds);
    }
  };
  auto stageB = [&](int t, int nh) {
    const int buf = t & 1, db = t << 6;
    #pragma unroll
    for (int j = 0; j < 2; ++j) {
      const int piece = j * 2 + wr;
      const int r = piece * 64 + nh * 32 + (wv & 3) * 8 + (lane >> 3);
      const int ksrc = ((lane & 7) * 8) ^ (((r >> 1) & 7) << 3);
      char* lds = (char*)&Bs[buf][0] + piece * 8192 + nh * 4096 + (wv & 3) * 1024;
      gload_lds16(Bb + (size_t)r * DIM + db + ksrc, lds);
    }
  };

  // ---- hoisted swizzled read addresses (per-lane constants) ----
  const int swz = ((l15 >> 1) & 7) << 4;       // byte bits 4-6
  const int kb0 = (l4 * 16) ^ swz;
  const int aB0 = wr * 16384 + l15 * 128 + kb0;
  const int aB1 = aB0 ^ 64;                    // ks=1 flips byte-bit 6
  const int bB0 = wc * 8192 + l15 * 128 + kb0;
  const int bB1 = bB0 ^ 64;

  short8 a0[8], a1[8], b0[4], b1[4];
  auto LDA0 = [&](int buf) {                   // mh=0: 8 x ds_read_b128
    const char* base = (const char*)&As[buf][0];
    #pragma unroll
    for (int f = 0; f < 4; ++f) {
      a0[f * 2 + 0] = *(const short8*)(base + aB0 + f * 2048);
      a0[f * 2 + 1] = *(const short8*)(base + aB1 + f * 2048);
    }
  };
  auto LDA1 = [&](int buf) {                   // mh=1: 8 x ds_read_b128
    const char* base = (const char*)&As[buf][0] + 8192;
    #pragma unroll
    for (int f = 0; f < 4; ++f) {
      a1[f * 2 + 0] = *(const short8*)(base + aB0 + f * 2048);
      a1[f * 2 + 1] = *(const short8*)(base + aB1 + f * 2048);
    }
  };
  auto LDB0 = [&](int buf) {
    const char* base = (const char*)&Bs[buf][0];
    #pragma unroll
    for (int g = 0; g < 2; ++g) {
      b0[g * 2 + 0] = *(const short8*)(base + bB0 + g * 2048);
      b0[g * 2 + 1] = *(const short8*)(base + bB1 + g * 2048);
    }
  };
  auto LDB1 = [&](int buf) {
    const char* base = (const char*)&Bs[buf][0] + 4096;
    #pragma unroll
    for (int g = 0; g < 2; ++g) {
      b1[g * 2 + 0] = *(const short8*)(base + bB0 + g * 2048);
      b1[g * 2 + 1] = *(const short8*)(base + bB1 + g * 2048);
    }
  };

  // ---- prologue: stage tiles 0 and 1; one conservative drain ----
  stageA(0, 0); stageA(0, 1); stageB(0, 0); stageB(0, 1);
  stageA(1, 0); stageA(1, 1); stageB(1, 0); stageB(1, 1);
  __syncthreads();   // vmcnt(0) + barrier: both tiles resident

  // ---- main loop: one barrier per K-tile; compiler schedules the region ----
  for (int u = 0; u < 16; ++u) {
    const int buf = u & 1;
    LDA0(buf); LDB0(buf); LDB1(buf);
    if (u < 15) { stageA(u + 1, 0); stageA(u + 1, 1); stageB(u + 1, 0); stageB(u + 1, 1); }
    #pragma unroll
    for (int ks = 0; ks < 2; ++ks)
      #pragma unroll
      for (int f = 0; f < 4; ++f)
        #pragma unroll
        for (int g = 0; g < 2; ++g)
          acc[f][g] = __builtin_amdgcn_mfma_f32_16x16x32_bf16(
              a0[f * 2 + ks], b0[g * 2 + ks], acc[f][g], 0, 0, 0);
    LDA1(buf);
    #pragma unroll
    for (int ks = 0; ks < 2; ++ks)
      #pragma unroll
      for (int f = 0; f < 4; ++f)
        #pragma unroll
        for (int g = 0; g < 2; ++g)
          acc[f][2 + g] = __builtin_amdgcn_mfma_f32_16x16x32_bf16(
              a0[f * 2 + ks], b1[g * 2 + ks], acc[f][2 + g], 0, 0, 0);
    #pragma unroll
    for (int ks = 0; ks < 2; ++ks)
      #pragma unroll
      for (int f = 0; f < 4; ++f) {
        #pragma unroll
        for (int g = 0; g < 2; ++g)
          acc[4 + f][g] = __builtin_amdgcn_mfma_f32_16x16x32_bf16(
              a1[f * 2 + ks], b0[g * 2 + ks], acc[4 + f][g], 0, 0, 0);
        #pragma unroll
        for (int g = 0; g < 2; ++g)
          acc[4 + f][2 + g] = __builtin_amdgcn_mfma_f32_16x16x32_bf16(
              a1[f * 2 + ks], b1[g * 2 + ks], acc[4 + f][2 + g], 0, 0, 0);
      }
    __syncthreads();   // vmcnt(0) (stage u+1 resident) + read-retire fence
  }

  // ---- gated epilogue: tanh(AV+Vb)*sigmoid(AU+Ub)*ww, reduce 16 lanes ----
  float partial[8][4];
  #pragma unroll
  for (int f = 0; f < 8; ++f)
    #pragma unroll
    for (int r = 0; r < 4; ++r) partial[f][r] = 0.f;

  #pragma unroll
  for (int p = 0; p < 2; ++p) {
    const int hl = (cb * 8 + wc * 2 + p) * 16 + l15;   // head-local h
    const float vb  = Vb[kh * HID + hl];
    const float ub  = Ub[kh * HID + hl];
    const float wwv = ww[kh * HID + hl];
    #pragma unroll
    for (int f = 0; f < 8; ++f)
      #pragma unroll
      for (int r = 0; r < 4; ++r) {
        const float xv = acc[f][2 * p][r] + vb;
        const float e2 = __expf(2.f * xv);
        const float av = 1.f - 2.f / (e2 + 1.f);       // tanh
        const float xu = acc[f][2 * p + 1][r] + ub;
        const float au = 1.f / (1.f + __expf(-xu));    // sigmoid
        partial[f][r] += av * au * wwv;
      }
  }
  #pragma unroll
  for (int s2 = 1; s2 < 16; s2 <<= 1)
    #pragma unroll
    for (int f = 0; f < 8; ++f)
      #pragma unroll
      for (int r = 0; r < 4; ++r)
        partial[f][r] += __shfl_xor(partial[f][r], s2, 64);

  if (l15 == 0) {
    const int j = cb * 4 + wc;   // 0..15 partial slot
    float* dst = part + ((size_t)j * NHEAD + kh) * N_PATCH;
    const int rbase = mt * 256 + wr * 128 + l4 * 4;
    #pragma unroll
    for (int f = 0; f < 8; ++f)
      #pragma unroll
      for (int r = 0; r < 4; ++r)
        dst[rbase + f * 16 + r] = partial[f][r];
  }
}

// ---------------- scores + per-chunk softmax partials (128 blocks) ----------------
__global__ void scores_part_kernel(const float* __restrict__ part,
                                   float* __restrict__ scores,
                                   float* __restrict__ spart) {
  const int k = blockIdx.x >> 3, c = blockIdx.x & 7;
  const int t = threadIdx.x;   // 256
  __shared__ float shm[4], shs[4];
  float v[4];
  float mx = -1e30f;
  #pragma unroll
  for (int i = 0; i < 4; ++i) {
    const int n = c * 1024 + i * 256 + t;
    float s = 0.f;
    #pragma unroll
    for (int j = 0; j < 16; ++j) s += part[((size_t)j * NHEAD + k) * N_PATCH + n];
    v[i] = s;
    scores[(size_t)k * N_PATCH + n] = s;
    mx = fmaxf(mx, s);
  }
  #pragma unroll
  for (int sft = 32; sft; sft >>= 1) mx = fmaxf(mx, __shfl_xor(mx, sft, 64));
  const int wv = t >> 6;
  if ((t & 63) == 0) shm[wv] = mx;
  __syncthreads();
  mx = fmaxf(fmaxf(shm[0], shm[1]), fmaxf(shm[2], shm[3]));
  float sum = 0.f;
  #pragma unroll
  for (int i = 0; i < 4; ++i) sum += __expf(v[i] - mx);
  #pragma unroll
  for (int sft = 32; sft; sft >>= 1) sum += __shfl_xor(sum, sft, 64);
  if ((t & 63) == 0) shs[wv] = sum;
  __syncthreads();
  if (t == 0) {
    spart[(k * 8 + c) * 2]     = mx;
    spart[(k * 8 + c) * 2 + 1] = shs[0] + shs[1] + shs[2] + shs[3];
  }
}

// ---------------- fused: head stats from spart; w[n]=sum_k softmax; partial col-sums (bf16 x) ----
__global__ void weighted_part_kernel(const unsigned short* __restrict__ xb,
                                     const float* __restrict__ scores,
                                     const float* __restrict__ spart,
                                     float* __restrict__ wp1,
                                     float* __restrict__ wp2) {
  __shared__ float wrow[128];
  __shared__ float sm[16], srz[16];
  const int d = blockIdx.x * 256 + threadIdx.x;  // grid.x = 4
  const int nc = blockIdx.y;                     // 64 chunks of 128 rows
  if (threadIdx.x < 16) {
    const int k = threadIdx.x;
    float m = -1e30f;
    #pragma unroll
    for (int c = 0; c < 8; ++c) m = fmaxf(m, spart[(k * 8 + c) * 2]);
    float S = 0.f;
    #pragma unroll
    for (int c = 0; c < 8; ++c)
      S += spart[(k * 8 + c) * 2 + 1] * __expf(spart[(k * 8 + c) * 2] - m);
    sm[k] = m; srz[k] = 1.f / S;
  }
  __syncthreads();
  if (threadIdx.x < 128) {
    const int n = nc * 128 + threadIdx.x;
    float s = 0.f;
    #pragma unroll
    for (int k = 0; k < NHEAD; ++k)
      s += __expf(scores[(size_t)k * N_PATCH + n] - sm[k]) * srz[k];
    wrow[threadIdx.x] = s;
  }
  __syncthreads();
  float a1 = 0.f, a2 = 0.f;
  for (int i = 0; i < 128; ++i) {
    unsigned uv = xb[(size_t)(nc * 128 + i) * DIM + d];
    float xv = __uint_as_float(uv << 16);
    a1 += wrow[i] * xv;
    a2 += xv;
  }
  wp1[nc * DIM + d] = a1;
  wp2[nc * DIM + d] = a2;
}

__global__ void reduce_vec_kernel(const float* __restrict__ wp1,
                                  const float* __restrict__ wp2,
                                  float* __restrict__ y1,
                                  float* __restrict__ mvec) {
  int d = blockIdx.x * 256 + threadIdx.x;
  float s1 = 0.f, s2 = 0.f;
  #pragma unroll
  for (int i = 0; i < 64; ++i) {
    s1 += wp1[i * DIM + d];
    s2 += wp2[i * DIM + d];
  }
  y1[d] = s1;
  mvec[d] = s2 * (1.f / (float)N_PATCH);
}

// ---------------- one-dispatch GEMV: in-block split-K (4 kc x 64 j), LDS reduce ----
__global__ void gemv_fused_kernel(const float* __restrict__ in,
                                  const float* __restrict__ W,
                                  const float* __restrict__ bias,
                                  const float* __restrict__ extra, float scale,
                                  int do_relu, float* __restrict__ out,
                                  int In, int Out) {
  __shared__ float red[4][64];
  const int jl = threadIdx.x & 63, kc = threadIdx.x >> 6;
  const int j = blockIdx.x * 64 + jl;
  const int chunk = In >> 2;
  const float* Wp = W + (size_t)(kc * chunk) * Out + j;
  const float* ip = in + kc * chunk;
  float acc = 0.f;
  #pragma unroll 4
  for (int d = 0; d < chunk; ++d) acc += ip[d] * Wp[(size_t)d * Out];
  if (kc) red[kc][jl] = acc;
  __syncthreads();
  if (kc == 0) {
    float v = bias[j] + acc + red[1][jl] + red[2][jl] + red[3][jl];
    if (extra) v += extra[j];
    v *= scale;
    if (do_relu) v = fmaxf(v, 0.f);
    out[j] = v;
  }
}

// ---------------- fused: c3 = relu(c2@cW3+cb3); logits = c3@cW4+cb4; softmax ----
__global__ void c3_final_kernel(const float* __restrict__ c2,
                                const float* __restrict__ W3,
                                const float* __restrict__ b3,
                                const float* __restrict__ W4,
                                const float* __restrict__ b4,
                                float* __restrict__ out) {
  __shared__ float c3s[256];
  __shared__ float logits[9];
  const int t = threadIdx.x;   // 256
  float acc = b3[t];
  #pragma unroll 4
  for (int d = 0; d < 512; ++d) acc += c2[d] * W3[(size_t)d * 256 + t];
  c3s[t] = fmaxf(acc, 0.f);
  __syncthreads();
  if (t < 9) {
    float l = b4[t];
    for (int d = 0; d < 256; ++d) l += c3s[d] * W4[d * 9 + t];
    logits[t] = l;
  }
  __syncthreads();
  if (t == 0) {
    float mx = logits[0];
    for (int j = 1; j < 9; ++j) mx = fmaxf(mx, logits[j]);
    float e[9], s = 0.f;
    for (int j = 0; j < 9; ++j) { e[j] = expf(logits[j] - mx); s += e[j]; }
    for (int j = 0; j < 9; ++j) out[j] = e[j] / s;
  }
}

extern "C" void kernel_launch(void* const* d_in, const int* in_sizes, int n_in,
                              void* d_out, int out_size, void* d_ws, size_t ws_size,
                              hipStream_t stream) {
  (void)in_sizes; (void)n_in; (void)out_size; (void)ws_size;
  const float* x   = (const float*)d_in[0];
  const float* Vw  = (const float*)d_in[1];
  const float* Vb  = (const float*)d_in[2];
  const float* Uw  = (const float*)d_in[3];
  const float* Ub  = (const float*)d_in[4];
  const float* ww  = (const float*)d_in[5];
  // d_in[6] = wb: constant per head -> softmax invariant -> unused
  const float* pW1 = (const float*)d_in[7];
  const float* pb1 = (const float*)d_in[8];
  const float* pW2 = (const float*)d_in[9];
  const float* pb2 = (const float*)d_in[10];
  const float* cW1 = (const float*)d_in[11];
  const float* cb1 = (const float*)d_in[12];
  const float* cW2 = (const float*)d_in[13];
  const float* cb2 = (const float*)d_in[14];
  const float* cW3 = (const float*)d_in[15];
  const float* cb3 = (const float*)d_in[16];
  const float* cW4 = (const float*)d_in[17];
  const float* cb4 = (const float*)d_in[18];
  float* out = (float*)d_out;

  char* ws = (char*)d_ws;
  size_t o = 0;
  auto alloc = [&](size_t bytes) -> char* {
    char* p = ws + o;
    o += (bytes + 255) & ~(size_t)255;
    return p;
  };
  unsigned short* xb  = (unsigned short*)alloc((size_t)N_PATCH * DIM * 2);      // 16 MB
  unsigned short* Wpt = (unsigned short*)alloc((size_t)NHEAD * 1024 * DIM * 2); // 32 MB
  float* part   = (float*)alloc((size_t)16 * NHEAD * N_PATCH * 4);              // 8 MB
  float* scores = (float*)alloc((size_t)NHEAD * N_PATCH * 4);
  float* spart  = (float*)alloc(NHEAD * 8 * 2 * 4);
  float* wp1    = (float*)alloc(64 * DIM * 4);
  float* wp2    = (float*)alloc(64 * DIM * 4);
  float* y1     = (float*)alloc(DIM * 4);
  float* mvec   = (float*)alloc(DIM * 4);
  float* h1     = (float*)alloc(HID * 4);
  float* aggr   = (float*)alloc(DIM * 4);
  float* c1     = (float*)alloc(1024 * 4);
  float* c2     = (float*)alloc(512 * 4);

  prep_kernel<<<4096, 256, 0, stream>>>(x, xb, Vw, Uw, Wpt);
  gemm_scores_kernel<<<2048, 512, 0, stream>>>(xb, Wpt, Vb, Ub, ww, part);
  scores_part_kernel<<<128, 256, 0, stream>>>(part, scores, spart);
  weighted_part_kernel<<<dim3(4, 64), 256, 0, stream>>>(xb, scores, spart, wp1, wp2);
  reduce_vec_kernel<<<4, 256, 0, stream>>>(wp1, wp2, y1, mvec);
  gemv_fused_kernel<<<8, 256, 0, stream>>>(mvec, pW1, pb1, nullptr, 1.f, 1, h1, DIM, HID);
  gemv_fused_kernel<<<16, 256, 0, stream>>>(h1, pW2, pb2, y1, 1.f / 17.f, 0, aggr, HID, DIM);
  gemv_fused_kernel<<<16, 256, 0, stream>>>(aggr, cW1, cb1, nullptr, 1.f, 1, c1, 1024, 1024);
  gemv_fused_kernel<<<8, 256, 0, stream>>>(c1, cW2, cb2, nullptr, 1.f, 1, c2, 1024, 512);
  c3_final_kernel<<<1, 256, 0, stream>>>(c2, cW3, cb3, cW4, cb4, out);
}